// Round 12
// baseline (470.188 us; speedup 1.0000x reference)
//
#include <hip/hip_runtime.h>

typedef __attribute__((ext_vector_type(8))) short bf16x8;
typedef __attribute__((ext_vector_type(4))) float f32x4;
typedef __attribute__((ext_vector_type(4))) unsigned uint32x4;

#define DEVFN __device__ __forceinline__

DEVFN short f2bf(float f) {
    union { float f; unsigned u; } v; v.f = f;
    unsigned r = (v.u + 0x7FFFu + ((v.u >> 16) & 1u)) >> 16;
    return (short)(unsigned short)r;
}
DEVFN float bf2f(short h) {
    union { unsigned u; float f; } v; v.u = ((unsigned)(unsigned short)h) << 16;
    return v.f;
}
// HW packed f32->bf16 (RNE, same as f2bf): 1 inst per 2 values
DEVFN unsigned pkbf(float a, float b) {
    unsigned r;
    asm("v_cvt_pk_bf16_f32 %0, %1, %2" : "=v"(r) : "v"(a), "v"(b));
    return r;
}

// async global->LDS, 16B per lane. lds dst must be wave-uniform-base + lane*16.
#define GLD_LDS16(gp, lp)                                                     \
    __builtin_amdgcn_global_load_lds(                                         \
        (const __attribute__((address_space(1))) unsigned*)(gp),              \
        (__attribute__((address_space(3))) unsigned*)(lp), 16, 0, 0)

// 32B AoS edge record: ONE random cache line per scattered edge write
struct __align__(16) ERec { int src; int dst; float cf; int pad; float4 ea; };

// Column permutation folded into weights: MFMA col c computes original col
// P(c) = (c&15)*8 + (c>>4); lane owns contiguous cols colbase*8..+7.

// ---------------- prep kernels ----------------

__global__ __launch_bounds__(128) void build_w1p_k(
    const float* __restrict__ Wb, const float* __restrict__ We1,
    const float* __restrict__ bb, const float* __restrict__ be1,
    float* __restrict__ W1p, float* __restrict__ b1p)
{
    int j = threadIdx.x;
    const float* B = We1 + 128 * 128;
    int i = blockIdx.x;
    if (i < 200) {
        float a = 0.f;
        for (int m = 0; m < 128; m++) a += Wb[i * 128 + m] * B[m * 128 + j];
        W1p[i * 128 + j] = a;
    } else {
        float a = be1[j];
        for (int m = 0; m < 128; m++) a += bb[m] * B[m * 128 + j];
        b1p[j] = a;
    }
}

// NEAREST-NEIGHBOR table, 1024 entries/channel, bf16 value only (1MB, L2-fit).
__global__ __launch_bounds__(128) void build_tab_k(
    const float* __restrict__ W1p, const float* __restrict__ b1p,
    short* __restrict__ tabN)
{
    int i = blockIdx.x;   // 0..1023
    int c = blockIdx.y;   // 0..3
    int j = threadIdx.x;
    float t = ((float)i + 0.5f) * (1.0f / 1024.0f);
    float acc = (c == 0) ? b1p[j] : 0.f;
    int kc = (int)(t * 49.f + 0.5f);
    for (int dk = -6; dk <= 6; dk++) {
        int k = kc + dk;
        if (k >= 0 && k < 50) {
            float d = t - (float)k * (1.f / 49.f);
            float g = expf(-1250.f * d * d);
            acc += g * W1p[(c * 50 + k) * 128 + j];
        }
    }
    tabN[((size_t)(c * 1024 + i)) * 128 + j] = f2bf(acc);
}

__global__ __launch_bounds__(256) void fold_plain_k(
    const float* __restrict__ W0, const float* __restrict__ W1,
    const float* __restrict__ W2, const float* __restrict__ W3,
    short* __restrict__ O0, short* __restrict__ O1,
    short* __restrict__ O2, short* __restrict__ O3)
{
    const float* W = (blockIdx.y == 0) ? W0 : (blockIdx.y == 1) ? W1 : (blockIdx.y == 2) ? W2 : W3;
    short* O = (blockIdx.y == 0) ? O0 : (blockIdx.y == 1) ? O1 : (blockIdx.y == 2) ? O2 : O3;
    int idx = blockIdx.x * 256 + threadIdx.x;
    int n = idx >> 8, ks = (idx >> 6) & 3, lane = idx & 63;
    int k8 = ks * 32 + (lane >> 4) * 8;
    int pcol = (lane & 15) * 8 + n;              // P(n*16 + colbase)
    bf16x8 fv;
    #pragma unroll
    for (int i2 = 0; i2 < 8; i2++) fv[i2] = f2bf(W[(k8 + i2) * 128 + pcol]);
    *(bf16x8*)(O + (size_t)idx * 8) = fv;
}

// ---------------- counting sort by dst ----------------

__global__ __launch_bounds__(256) void hist_k(
    const int* __restrict__ dstI, int* __restrict__ cnt, int E)
{
    int e = blockIdx.x * 256 + threadIdx.x;
    if (e < E) atomicAdd(&cnt[dstI[e]], 1);
}

__global__ __launch_bounds__(256) void scan1_k(
    const int* __restrict__ cnt, int Nn, int* __restrict__ posE, int* __restrict__ bsum)
{
    __shared__ int s[256];
    int t = threadIdx.x, g = blockIdx.x * 256 + t;
    int v = (g < Nn) ? cnt[g] : 0;
    s[t] = v;
    __syncthreads();
    for (int off = 1; off < 256; off <<= 1) {
        int u = (t >= off) ? s[t - off] : 0;
        __syncthreads();
        s[t] += u;
        __syncthreads();
    }
    if (g < Nn) posE[g] = s[t] - v;
    if (t == 255) bsum[blockIdx.x] = s[255];
}

__global__ __launch_bounds__(256) void scan2_k(int* __restrict__ bsum, int nb)
{
    __shared__ int s[256];
    int t = threadIdx.x;
    int v = (t < nb) ? bsum[t] : 0;
    s[t] = v;
    __syncthreads();
    for (int off = 1; off < 256; off <<= 1) {
        int u = (t >= off) ? s[t - off] : 0;
        __syncthreads();
        s[t] += u;
        __syncthreads();
    }
    if (t < nb) bsum[t] = s[t] - v;
}

__global__ __launch_bounds__(256) void fix_k(
    const int* __restrict__ posE, const int* __restrict__ bsum,
    int* __restrict__ pos2, int Nn)
{
    int id = blockIdx.x * 256 + threadIdx.x;
    if (id < Nn) pos2[id] = posE[id] + bsum[id >> 8];
}

__global__ __launch_bounds__(256) void scat_k(
    const int* __restrict__ srcI, const int* __restrict__ dstI,
    const float4* __restrict__ ea4, int* __restrict__ pos2,
    ERec* __restrict__ rec, int E)
{
    int e = blockIdx.x * 256 + threadIdx.x;
    if (e >= E) return;
    int d = dstI[e];
    int p = atomicAdd(&pos2[d], 1);
    float4 ev = ea4[e];
    ERec r;
    r.src = srcI[e]; r.dst = d;
    r.cf = cosf(1.57079632679f * ev.w); r.pad = 0;
    r.ea = ev;
    rec[p] = r;    // one 32B record = one cache line (2x dwordx4 stores)
}
// NOTE: after scat_k, pos2[d] == segment END offset (start + count).

// ---------------- fused node precompute (direct-global B, small grid) ----------------
__global__ __launch_bounds__(256, 4) void node_all_k(
    const float* __restrict__ x, int M,
    const short* __restrict__ bp3,
    const float* __restrict__ bd, const float* __restrict__ vv,
    short* __restrict__ xd, short* __restrict__ zaccb,
    short* __restrict__ xs1b, short* __restrict__ xt1b)
{
    int tid = threadIdx.x;
    int wave = tid >> 6, lane = tid & 63;
    int kgrp = lane >> 4, colbase = lane & 15;
    int chunk = blockIdx.x;
    int rowA = chunk * 64 + wave * 16 + colbase;
    bool rv = rowA < M;

    bf16x8 af[4];
    #pragma unroll
    for (int ks = 0; ks < 4; ks++) {
        bf16x8 v = (bf16x8){0,0,0,0,0,0,0,0};
        if (rv) {
            const float* ap = x + (size_t)rowA * 128 + ks * 32 + kgrp * 8;
            float4 f0 = ((const float4*)ap)[0];
            float4 f1 = ((const float4*)ap)[1];
            v[0] = f2bf(f0.x); v[1] = f2bf(f0.y); v[2] = f2bf(f0.z); v[3] = f2bf(f0.w);
            v[4] = f2bf(f1.x); v[5] = f2bf(f1.y); v[6] = f2bf(f1.z); v[7] = f2bf(f1.w);
        }
        af[ks] = v;
    }

    float bcol[8], vcol[8];
    *(float4*)&bcol[0] = *(const float4*)(bd + colbase * 8);
    *(float4*)&bcol[4] = *(const float4*)(bd + colbase * 8 + 4);
    *(float4*)&vcol[0] = *(const float4*)(vv + colbase * 8);
    *(float4*)&vcol[4] = *(const float4*)(vv + colbase * 8 + 4);

    int rbase = chunk * 64 + wave * 16 + kgrp * 4;

    for (int b = 0; b < 3; b++) {
        const short* Bb = bp3 + (size_t)b * 16384;
        f32x4 acc[8];
        #pragma unroll
        for (int n = 0; n < 8; n++) acc[n] = (f32x4){0.f, 0.f, 0.f, 0.f};
        #pragma unroll
        for (int ks = 0; ks < 4; ks++) {
            #pragma unroll
            for (int n = 0; n < 8; n++) {
                bf16x8 bf = *(const bf16x8*)(Bb + ((size_t)((n * 4 + ks) * 64 + lane)) * 8);
                acc[n] = __builtin_amdgcn_mfma_f32_16x16x32_bf16(af[ks], bf, acc[n], 0, 0, 0);
            }
        }
        if (b == 0) {
            #pragma unroll
            for (int r = 0; r < 4; r++) {
                int row = rbase + r;
                if (row < M) {
                    bf16x8 xo, zo;
                    #pragma unroll
                    for (int n = 0; n < 8; n++) {
                        float val = acc[n][r] + bcol[n];
                        xo[n] = f2bf(val);
                        zo[n] = f2bf(vcol[n] * val);
                    }
                    *(bf16x8*)(xd    + (size_t)row * 128 + colbase * 8) = xo;
                    *(bf16x8*)(zaccb + (size_t)row * 128 + colbase * 8) = zo;
                }
            }
        } else {
            short* outp = (b == 1) ? xs1b : xt1b;
            #pragma unroll
            for (int r = 0; r < 4; r++) {
                int row = rbase + r;
                if (row < M) {
                    bf16x8 o;
                    #pragma unroll
                    for (int n = 0; n < 8; n++) o[n] = f2bf(acc[n][r]);
                    *(bf16x8*)(outp + (size_t)row * 128 + colbase * 8) = o;
                }
            }
        }
    }
}

// ---------------- edge pass 1: BALANCED PERSISTENT waves ---------------------
// 1024 blocks (all resident). Each wave owns a CONTIGUOUS range of quads.
// Nearest-1024 bf16 table: 1MB L2-resident footprint, no fraction math.
// lane = esub(2b) x colgroup(4b): lane handles edge q*4+esub, cols colg*8..+7

#define EZ_ISSUE(XS, XT, TT, qi) do {                                          \
    int e_ = (qi) * 4 + esub;                                                  \
    int ec_ = e_ < Etot ? e_ : Etot - 1;                                       \
    const ERec* rp_ = rec + ec_;                                               \
    int4 h_ = *(const int4*)rp_;                                               \
    float4 ea_ = *(const float4*)((const char*)rp_ + 16);                      \
    XS = *(const bf16x8*)(xs1b + (size_t)h_.x * 128 + colg * 8);               \
    XT = *(const bf16x8*)(xt1b + (size_t)h_.y * 128 + colg * 8);               \
    float tv_[4] = {ea_.x, ea_.y, ea_.z, ea_.w};                               \
    _Pragma("unroll")                                                          \
    for (int c_ = 0; c_ < 4; c_++) {                                           \
        int i0_ = (int)(tv_[c_] * 1024.f);                                     \
        i0_ = i0_ < 0 ? 0 : (i0_ > 1023 ? 1023 : i0_);                         \
        TT[c_] = *(const bf16x8*)(tabN +                                       \
            ((size_t)(c_ * 1024 + i0_) * 128) + colg * 8);                     \
    }                                                                          \
} while (0)

#define EZ_CONSUME(XS, XT, TT, qi) do {                                        \
    int e_ = (qi) * 4 + esub;                                                  \
    float p_[8];                                                               \
    _Pragma("unroll")                                                          \
    for (int j_ = 0; j_ < 8; j_++) p_[j_] = bf2f(XS[j_]) + bf2f(XT[j_]);       \
    _Pragma("unroll")                                                          \
    for (int c_ = 0; c_ < 4; c_++) {                                           \
        _Pragma("unroll")                                                      \
        for (int j_ = 0; j_ < 8; j_++) p_[j_] += bf2f(TT[c_][j_]);             \
    }                                                                          \
    bool valid_ = e_ < Etot;                                                   \
    _Pragma("unroll")                                                          \
    for (int j_ = 0; j_ < 8; j_++) {                                           \
        float z_ = p_[j_] >= 0.f ? p_[j_] : 0.01f * p_[j_];                    \
        p_[j_] = z_;                                                           \
        float m_ = valid_ ? z_ : 0.f;                                          \
        sacc[j_] += m_;                                                        \
        qacc[j_] = fmaf(m_, z_, qacc[j_]);                                     \
    }                                                                          \
    if (valid_) {                                                              \
        uint32x4 ov_ = {pkbf(p_[0], p_[1]), pkbf(p_[2], p_[3]),                \
                        pkbf(p_[4], p_[5]), pkbf(p_[6], p_[7])};               \
        *(uint32x4*)(z1 + (size_t)e_ * 128 + colg * 8) = ov_;                  \
    }                                                                          \
} while (0)

__global__ __launch_bounds__(256) void edge_z1_k(
    const short* __restrict__ xs1b, const short* __restrict__ xt1b,
    const short* __restrict__ tabN,
    const ERec* __restrict__ rec,
    short* __restrict__ z1, float* __restrict__ stats, int Etot)
{
    int tid = threadIdx.x, wave = tid >> 6, lane = tid & 63;
    int colg = lane & 15, esub = lane >> 4;

    int gw = blockIdx.x * 4 + wave;          // global wave id
    int W = gridDim.x * 4;                   // total waves
    int nq = (Etot + 3) >> 2;                // total 4-edge quads
    int q0 = (int)(((long long)gw * nq) / W);
    int q1 = (int)(((long long)(gw + 1) * nq) / W);
    int nsteps = q1 - q0;                    // balanced to +-1

    float sacc[8], qacc[8];
    #pragma unroll
    for (int j = 0; j < 8; j++) { sacc[j] = 0.f; qacc[j] = 0.f; }

    bf16x8 xsA, xtA, ttA[4];
    bf16x8 xsB, xtB, ttB[4];
    bf16x8 xsC, xtC, ttC[4];

    if (nsteps > 0) {
        EZ_ISSUE(xsA, xtA, ttA, q0 + 0);
        EZ_ISSUE(xsB, xtB, ttB, q0 + 1);     // clamped if overshoot
        int st = 0;
        for (; st + 3 <= nsteps; st += 3) {
            EZ_ISSUE(xsC, xtC, ttC, q0 + st + 2);
            EZ_CONSUME(xsA, xtA, ttA, q0 + st);
            EZ_ISSUE(xsA, xtA, ttA, q0 + st + 3);
            EZ_CONSUME(xsB, xtB, ttB, q0 + st + 1);
            EZ_ISSUE(xsB, xtB, ttB, q0 + st + 4);
            EZ_CONSUME(xsC, xtC, ttC, q0 + st + 2);
        }
        if (st < nsteps)
            EZ_CONSUME(xsA, xtA, ttA, q0 + st);
        if (st + 1 < nsteps)
            EZ_CONSUME(xsB, xtB, ttB, q0 + st + 1);
    }

    // pre-reduce across the 4 esub lanes sharing a column group (lanes
    // colg, colg+16, colg+32, colg+48) -> 4x fewer LDS atomics
    #pragma unroll
    for (int j = 0; j < 8; j++) {
        sacc[j] += __shfl_xor(sacc[j], 16);
        sacc[j] += __shfl_xor(sacc[j], 32);
        qacc[j] += __shfl_xor(qacc[j], 16);
        qacc[j] += __shfl_xor(qacc[j], 32);
    }

    __shared__ float lS[128], lQ[128];
    if (tid < 128) { lS[tid] = 0.f; lQ[tid] = 0.f; }
    __syncthreads();
    if (esub == 0) {
        #pragma unroll
        for (int j = 0; j < 8; j++) {
            atomicAdd(&lS[colg * 8 + j], sacc[j]);
            atomicAdd(&lQ[colg * 8 + j], qacc[j]);
        }
    }
    __syncthreads();
    if (tid < 128) {
        int rep = blockIdx.x & 15;
        atomicAdd(&stats[rep * 256 + tid], lS[tid]);
        atomicAdd(&stats[rep * 256 + 128 + tid], lQ[tid]);
    }
}

// ---------------- segmented reduce over dst-sorted edges (no atomics) ----
// 8 dsts/wave: doubles wave count -> keeps SIMDs fed through drain.
__global__ __launch_bounds__(256) void segred_k(
    const short* __restrict__ cond, const short* __restrict__ xd,
    const ERec* __restrict__ rec, const int* __restrict__ endPos,
    short* __restrict__ zaccb, int Nn)
{
    int tid = threadIdx.x, wave = tid >> 6, lane = tid & 63;
    int colg = lane & 7;        // 8 col-groups x 16 cols
    int esub = lane >> 3;       // 8 edges in parallel
    int d0 = blockIdx.x * 32 + wave * 8;

    for (int i = 0; i < 8; i++) {
        int d = d0 + i;
        if (d >= Nn) break;
        int s0 = (d == 0) ? 0 : endPos[d - 1];
        int s1 = endPos[d];
        if (s1 <= s0) continue;            // empty segment: zaccb already = m_t

        float acc[16];
        #pragma unroll
        for (int j = 0; j < 16; j++) acc[j] = 0.f;

        for (int t = s0 + esub; t < s1; t += 8) {
            const short* cp = cond + (size_t)t * 128 + colg * 16;
            bf16x8 c0 = *(const bf16x8*)cp;
            bf16x8 c1 = *(const bf16x8*)(cp + 8);
            int s = rec[t].src;
            const short* xp = xd + (size_t)s * 128 + colg * 16;
            bf16x8 x0 = *(const bf16x8*)xp;
            bf16x8 x1 = *(const bf16x8*)(xp + 8);
            #pragma unroll
            for (int j = 0; j < 8; j++) {
                acc[j]     += bf2f(c0[j]) * bf2f(x0[j]);
                acc[8 + j] += bf2f(c1[j]) * bf2f(x1[j]);
            }
        }

        #pragma unroll
        for (int j = 0; j < 16; j++) {
            acc[j] += __shfl_xor(acc[j], 8);
            acc[j] += __shfl_xor(acc[j], 16);
            acc[j] += __shfl_xor(acc[j], 32);
        }

        if (esub == 0) {
            short* zp = zaccb + (size_t)d * 128 + colg * 16;
            bf16x8 z0 = *(const bf16x8*)zp;
            bf16x8 z1 = *(const bf16x8*)(zp + 8);
            bf16x8 o0, o1;
            #pragma unroll
            for (int j = 0; j < 8; j++) {
                o0[j] = f2bf(bf2f(z0[j]) + acc[j]);
                o1[j] = f2bf(bf2f(z1[j]) + acc[8 + j]);
            }
            *(bf16x8*)zp = o0;
            *(bf16x8*)(zp + 8) = o1;
        }
    }
}

// ---------------- persistent MFMA GEMM, balanced ranges, unroll-2 A pipeline --
// FOLD=1: BN-fold computed IN-PROLOGUE (removes fold_k dispatches from the
// critical path): s,t from stats -> fold W into ldsB -> folded bias into LDS.
// Same arithmetic/order as the old fold_k (bitwise-identical results).
// FOLD=0: B staged from pre-folded Bp via global_load_lds (plain weights).
// EPI 2: z=lrelu(val); out bf16; BN stats
// EPI 3: out bf16 = rec[row].cf * val   (cond_filter, written in-place over A)
// EPI 4: out fp32 = val + xres

#define PG_LOADA(AF, ci) do {                                                  \
    int rowA_ = (ci) * 64 + wave * 16 + colbase;                               \
    bool rv_ = ((ci) < cend) && (rowA_ < M);                                   \
    _Pragma("unroll")                                                          \
    for (int ks_ = 0; ks_ < 4; ks_++)                                          \
        AF[ks_] = rv_ ? *(const bf16x8*)(A + (size_t)rowA_ * 128 + ks_ * 32 + kgrp * 8) \
                      : (bf16x8){0,0,0,0,0,0,0,0};                             \
} while (0)

#define PG_PROC(AF, ci) do {                                                   \
    int rbase_ = (ci) * 64 + wave * 16 + kgrp * 4;                             \
    f32x4 acc_[8];                                                             \
    _Pragma("unroll")                                                          \
    for (int n_ = 0; n_ < 8; n_++) acc_[n_] = (f32x4){0.f, 0.f, 0.f, 0.f};     \
    _Pragma("unroll")                                                          \
    for (int ks_ = 0; ks_ < 4; ks_++) {                                        \
        _Pragma("unroll")                                                      \
        for (int n_ = 0; n_ < 8; n_++) {                                       \
            bf16x8 bf_ = *(const bf16x8*)(ldsB + ((size_t)((n_ * 4 + ks_) * 64 + lane)) * 8); \
            acc_[n_] = __builtin_amdgcn_mfma_f32_16x16x32_bf16(AF[ks_], bf_, acc_[n_], 0, 0, 0); \
        }                                                                      \
    }                                                                          \
    if (EPI == 2) {                                                            \
        short* outh_ = (short*)out;                                            \
        _Pragma("unroll")                                                      \
        for (int r_ = 0; r_ < 4; r_++) {                                       \
            int row_ = rbase_ + r_;                                            \
            float zz_[8];                                                      \
            _Pragma("unroll")                                                  \
            for (int n_ = 0; n_ < 8; n_++) {                                   \
                float z_ = acc_[n_][r_] + bcol[n_];                            \
                z_ = z_ >= 0.f ? z_ : 0.01f * z_;                              \
                if (row_ >= M) z_ = 0.f;                                       \
                sreg[n_] += z_; qreg[n_] += z_ * z_;                           \
                zz_[n_] = z_;                                                  \
            }                                                                  \
            if (row_ < M) {                                                    \
                uint32x4 ov_ = {pkbf(zz_[0], zz_[1]), pkbf(zz_[2], zz_[3]),    \
                                pkbf(zz_[4], zz_[5]), pkbf(zz_[6], zz_[7])};   \
                *(uint32x4*)(outh_ + (size_t)row_ * 128 + colbase * 8) = ov_;  \
            }                                                                  \
        }                                                                      \
    } else if (EPI == 3) {                                                     \
        short* outh_ = (short*)out;                                            \
        _Pragma("unroll")                                                      \
        for (int r_ = 0; r_ < 4; r_++) {                                       \
            int row_ = rbase_ + r_;                                            \
            if (row_ < M) {                                                    \
                float cfv_ = rec[row_].cf;                                     \
                uint32x4 ov_;                                                  \
                _Pragma("unroll")                                              \
                for (int q_ = 0; q_ < 4; q_++)                                 \
                    ov_[q_] = pkbf(cfv_ * (acc_[2 * q_][r_] + bcol[2 * q_]),   \
                                   cfv_ * (acc_[2 * q_ + 1][r_] + bcol[2 * q_ + 1])); \
                *(uint32x4*)(outh_ + (size_t)row_ * 128 + colbase * 8) = ov_;  \
            }                                                                  \
        }                                                                      \
    } else if (EPI == 4) {                                                     \
        float* outf_ = (float*)out;                                            \
        _Pragma("unroll")                                                      \
        for (int r_ = 0; r_ < 4; r_++) {                                       \
            int row_ = rbase_ + r_;                                            \
            if (row_ < M) {                                                    \
                const float4* xr_ = (const float4*)(xres + (size_t)row_ * 128 + colbase * 8); \
                float4 x0_ = xr_[0], x1_ = xr_[1];                             \
                float4 o0_, o1_;                                               \
                o0_.x = acc_[0][r_] + bcol[0] + x0_.x;                         \
                o0_.y = acc_[1][r_] + bcol[1] + x0_.y;                         \
                o0_.z = acc_[2][r_] + bcol[2] + x0_.z;                         \
                o0_.w = acc_[3][r_] + bcol[3] + x0_.w;                         \
                o1_.x = acc_[4][r_] + bcol[4] + x1_.x;                         \
                o1_.y = acc_[5][r_] + bcol[5] + x1_.y;                         \
                o1_.z = acc_[6][r_] + bcol[6] + x1_.z;                         \
                o1_.w = acc_[7][r_] + bcol[7] + x1_.w;                         \
                float4* op_ = (float4*)(outf_ + (size_t)row_ * 128 + colbase * 8); \
                op_[0] = o0_; op_[1] = o1_;                                    \
            }                                                                  \
        }                                                                      \
    }                                                                          \
} while (0)

template<int EPI, int FOLD>
__global__ __launch_bounds__(256, 2) void pgemm_k(
    const short* __restrict__ A, int M,
    const short* __restrict__ Bp,                 // FOLD==0
    const float* __restrict__ Wf,                 // FOLD==1: raw fp32 weights
    const float* __restrict__ statsG, const float* __restrict__ gamma,
    const float* __restrict__ beta, float invNs,
    const float* __restrict__ bias,
    void* __restrict__ out, float* __restrict__ stats,
    const ERec* __restrict__ rec, const float* __restrict__ xres)
{
    __shared__ __align__(16) short ldsB[16384];
    __shared__ float lS[128], lQ[128], lB[128];
    int tid = threadIdx.x;
    int wave = tid >> 6, lane = tid & 63;
    int kgrp = lane >> 4, colbase = lane & 15;

    if (FOLD) {
        // BN stats -> per-column scale s (lS) and shift t (lQ)
        if (tid < 128) {
            float sum = 0.f, sq = 0.f;
            for (int r = 0; r < 16; r++) {
                sum += statsG[r * 256 + tid];
                sq  += statsG[r * 256 + 128 + tid];
            }
            float m = sum * invNs;
            float var = sq * invNs - m * m;
            float rs = rsqrtf(var + 1e-5f);
            float s = rs * gamma[tid];
            lS[tid] = s;
            lQ[tid] = beta[tid] - m * s;
        }
        __syncthreads();
        // fold weights into ldsB (same layout/order as old fold_k)
        #pragma unroll
        for (int i = 0; i < 8; i++) {
            int idx = i * 256 + tid;
            int n = idx >> 8, ks4 = (idx >> 6) & 3, ln = idx & 63;
            int k8 = ks4 * 32 + (ln >> 4) * 8;
            int pcol = (ln & 15) * 8 + n;
            bf16x8 fv;
            #pragma unroll
            for (int i2 = 0; i2 < 8; i2++)
                fv[i2] = f2bf(lS[k8 + i2] * Wf[(k8 + i2) * 128 + pcol]);
            *(bf16x8*)(ldsB + (size_t)idx * 8) = fv;
        }
        // folded bias: b[j] = bias[j] + sum_k t[k]*W[k,j]
        if (tid < 128) {
            float b = bias[tid];
            for (int k = 0; k < 128; k++) b += lQ[k] * Wf[k * 128 + tid];
            lB[tid] = b;
        }
        __syncthreads();   // ldsB + lB ready; lS/lQ free after this point
        if (EPI == 2 && tid < 128) { lS[tid] = 0.f; lQ[tid] = 0.f; }
    } else {
        // async stage pre-folded B -> LDS: 8 issues x 256 lanes x 16B = 32KB
        #pragma unroll
        for (int i = 0; i < 8; i++) {
            int off = (i * 256 + wave * 64 + lane) * 8;
            GLD_LDS16(Bp + off, ldsB + off);
        }
        if (EPI == 2 && tid < 128) { lS[tid] = 0.f; lQ[tid] = 0.f; }
    }

    int nch = (M + 63) >> 6;
    int cbeg = (int)(((long long)blockIdx.x * nch) / gridDim.x);
    int cend = (int)(((long long)(blockIdx.x + 1) * nch) / gridDim.x);

    // prologue: A fragments for the first two chunks
    bf16x8 afA[4], afB[4];
    PG_LOADA(afA, cbeg);
    PG_LOADA(afB, cbeg + 1);

    float bcol[8];
    if (FOLD) {
        #pragma unroll
        for (int n = 0; n < 8; n++) bcol[n] = lB[colbase * 8 + n];
    } else {
        *(float4*)&bcol[0] = *(const float4*)(bias + colbase * 8);
        *(float4*)&bcol[4] = *(const float4*)(bias + colbase * 8 + 4);
    }

    float sreg[8], qreg[8];
    if (EPI == 2) {
        #pragma unroll
        for (int n = 0; n < 8; n++) { sreg[n] = 0.f; qreg[n] = 0.f; }
    }

    __syncthreads();   // B staged (GLD drained / ds_writes visible)

    int c = cbeg;
    for (; c + 1 < cend; c += 2) {
        PG_PROC(afA, c);            // consume afA (loads issued 2 chunks ago)
        PG_LOADA(afA, c + 2);       // refill AFTER consumption: 2-chunk lead
        PG_PROC(afB, c + 1);
        PG_LOADA(afB, c + 3);
    }
    if (c < cend)
        PG_PROC(afA, c);            // odd tail

    if (EPI == 2) {
        // pre-reduce across the 4 kgrp lanes sharing colbase -> 4x fewer atomics
        #pragma unroll
        for (int n = 0; n < 8; n++) {
            sreg[n] += __shfl_xor(sreg[n], 16);
            sreg[n] += __shfl_xor(sreg[n], 32);
            qreg[n] += __shfl_xor(qreg[n], 16);
            qreg[n] += __shfl_xor(qreg[n], 32);
        }
        __syncthreads();
        if (kgrp == 0) {
            #pragma unroll
            for (int n = 0; n < 8; n++) {
                atomicAdd(&lS[colbase * 8 + n], sreg[n]);
                atomicAdd(&lQ[colbase * 8 + n], qreg[n]);
            }
        }
        __syncthreads();
        if (tid < 128) {
            int rep = blockIdx.x & 15;
            atomicAdd(&stats[rep * 256 + tid], lS[tid]);
            atomicAdd(&stats[rep * 256 + 128 + tid], lQ[tid]);
        }
    }
}

extern "C" void kernel_launch(void* const* d_in, const int* in_sizes, int n_in,
                              void* d_out, int out_size, void* d_ws, size_t ws_size,
                              hipStream_t stream)
{
    const float* x    = (const float*)d_in[0];
    const float* ea   = (const float*)d_in[1];
    const int*   eidx = (const int*)d_in[2];
    const float* Wb   = (const float*)d_in[3];
    const float* bb   = (const float*)d_in[4];
    const float* We1  = (const float*)d_in[5];
    const float* be1  = (const float*)d_in[6];
    const float* ge1  = (const float*)d_in[7];
    const float* bte1 = (const float*)d_in[8];
    const float* We2  = (const float*)d_in[9];
    const float* be2  = (const float*)d_in[10];
    const float* ge2  = (const float*)d_in[11];
    const float* bte2 = (const float*)d_in[12];
    const float* We3  = (const float*)d_in[13];
    const float* be3  = (const float*)d_in[14];
    const float* Wd   = (const float*)d_in[15];
    const float* bd   = (const float*)d_in[16];
    const float* vv   = (const float*)d_in[17];
    const float* Wn1  = (const float*)d_in[18];
    const float* bn1  = (const float*)d_in[19];
    const float* gn   = (const float*)d_in[20];
    const float* btn  = (const float*)d_in[21];
    const float* Wn2  = (const float*)d_in[22];
    const float* bn2  = (const float*)d_in[23];

    const int NN = in_sizes[0] / 128;   // 50000
    const int EE = in_sizes[1] / 4;     // 300000

    char* ws = (char*)d_ws;
    size_t oEZ   = 0;
    size_t oXD   = oEZ   + (size_t)EE * 256;
    size_t oXS   = oXD   + (size_t)NN * 256;
    size_t oXT   = oXS   + (size_t)NN * 256;
    size_t oZACC = oXT   + (size_t)NN * 256;
    size_t oZN   = oZACC + (size_t)NN * 256;
    size_t oTAB  = oZN   + (size_t)NN * 256;
    size_t oW1P  = oTAB  + (size_t)4 * 1024 * 256;   // nearest table: 1MB
    size_t oB1P  = oW1P  + (size_t)200 * 512;
    size_t oBP   = oB1P  + 512;
    size_t oBIAS = oBP   + (size_t)7 * 32768;
    size_t oST   = oBIAS + (size_t)7 * 512;
    size_t oCNT  = oST   + 49152;
    size_t oPOS  = oCNT  + 201728;
    size_t oBSUM = oPOS  + 201728;
    size_t oPOS2 = oBSUM + 1024;
    size_t oREC  = (oPOS2 + 201728 + 31) & ~(size_t)31;   // EE x 32B records

    short* eZ    = (short*)(ws + oEZ);
    short* xd    = (short*)(ws + oXD);
    short* xs1b  = (short*)(ws + oXS);
    short* xt1b  = (short*)(ws + oXT);
    short* zaccb = (short*)(ws + oZACC);
    short* zn    = (short*)(ws + oZN);
    short* tabN  = (short*)(ws + oTAB);
    float* W1p   = (float*)(ws + oW1P);
    float* b1p   = (float*)(ws + oB1P);
    short* bp    = (short*)(ws + oBP);
    short* BpN1  = bp + 5 * 16384;
    float* st1   = (float*)(ws + oST);
    float* st2   = st1 + 4096;
    float* stN   = st1 + 8192;
    int*   cnt   = (int*)(ws + oCNT);
    int*   posE  = (int*)(ws + oPOS);
    int*   bsum  = (int*)(ws + oBSUM);
    int*   pos2  = (int*)(ws + oPOS2);
    ERec*  rec   = (ERec*)(ws + oREC);

    hipMemsetAsync(ws + oST, 0, 49152 + 201728, stream);

    build_w1p_k<<<201, 128, 0, stream>>>(Wb, We1, bb, be1, W1p, b1p);
    build_tab_k<<<dim3(1024, 4), 128, 0, stream>>>(W1p, b1p, tabN);
    fold_plain_k<<<dim3(8, 4), 256, 0, stream>>>(
        Wd, We1, We1 + 256 * 128, Wn1, bp, bp + 16384, bp + 2 * 16384, BpN1);

    int nchN = (NN + 63) / 64;
    int nchE = (EE + 63) / 64;
    int nbN = (NN + 255) / 256;
    int nbE = (EE + 255) / 256;
    int nbSeg = (NN + 31) / 32;         // segred: 32 dsts/block (8/wave)

    // persistent grids: at most the resident capacity (4 blocks/CU x 256 CU)
    int gridEz = 1024;
    int gridE = nchE < 1024 ? nchE : 1024;
    int gridN = nchN < 1024 ? nchN : 1024;   // 782: exactly 1 chunk/block

    // fused node precompute: xd/zacc, xs1, xt1  (reads x once)
    node_all_k<<<nchN, 256, 0, stream>>>(x, NN, bp, bd, vv, xd, zaccb, xs1b, xt1b);

    // counting sort by dst
    hist_k<<<nbE, 256, 0, stream>>>(eidx + EE, cnt, EE);
    scan1_k<<<nbN, 256, 0, stream>>>(cnt, NN, posE, bsum);
    scan2_k<<<1, 256, 0, stream>>>(bsum, nbN);
    fix_k<<<nbN, 256, 0, stream>>>(posE, bsum, pos2, NN);
    scat_k<<<nbE, 256, 0, stream>>>(eidx, eidx + EE, (const float4*)ea, pos2,
                                    rec, EE);

    edge_z1_k<<<gridEz, 256, 0, stream>>>(xs1b, xt1b, tabN, rec, eZ, st1, EE);

    // z2 = lrelu(z1 @ fold(We2,st1) + b) with stats -> st2  (fold in-prologue)
    pgemm_k<2, 1><<<gridE, 256, 0, stream>>>(eZ, EE, nullptr, We2,
        st1, ge1, bte1, 1.f / (float)EE, be2, eZ, st2, nullptr, nullptr);

    // cond = cf * (z2 @ fold(We3,st2) + b), in-place over eZ (fold in-prologue)
    pgemm_k<3, 1><<<gridE, 256, 0, stream>>>(eZ, EE, nullptr, We3,
        st2, ge2, bte2, 1.f / (float)EE, be3, eZ, nullptr, rec, nullptr);

    // segmented reduction (dst-sorted, pos2 = segment end offsets): zaccb += sum cond*xd[src]
    segred_k<<<nbSeg, 256, 0, stream>>>(eZ, xd, rec, pos2, zaccb, NN);

    // zn = lrelu(zacc @ Wn1 + bn1) with stats -> stN  (plain pre-folded B)
    pgemm_k<2, 0><<<gridN, 256, 0, stream>>>(zaccb, NN, BpN1, nullptr,
        nullptr, nullptr, nullptr, 0.f, bn1, zn, stN, nullptr, nullptr);

    // out = zn @ fold(Wn2,stN) + b + x  (fold in-prologue)
    pgemm_k<4, 1><<<gridN, 256, 0, stream>>>(zn, NN, nullptr, Wn2,
        stN, gn, btn, 1.f / (float)NN, bn2, d_out, nullptr, nullptr, x);
}

// Round 13
// 384.180 us; speedup vs baseline: 1.2239x; 1.2239x over previous
//
#include <hip/hip_runtime.h>

typedef __attribute__((ext_vector_type(8))) short bf16x8;
typedef __attribute__((ext_vector_type(4))) float f32x4;
typedef __attribute__((ext_vector_type(4))) unsigned uint32x4;

#define DEVFN __device__ __forceinline__

DEVFN short f2bf(float f) {
    union { float f; unsigned u; } v; v.f = f;
    unsigned r = (v.u + 0x7FFFu + ((v.u >> 16) & 1u)) >> 16;
    return (short)(unsigned short)r;
}
DEVFN float bf2f(short h) {
    union { unsigned u; float f; } v; v.u = ((unsigned)(unsigned short)h) << 16;
    return v.f;
}
// HW packed f32->bf16 (RNE, same as f2bf): 1 inst per 2 values
DEVFN unsigned pkbf(float a, float b) {
    unsigned r;
    asm("v_cvt_pk_bf16_f32 %0, %1, %2" : "=v"(r) : "v"(a), "v"(b));
    return r;
}

// async global->LDS, 16B per lane. lds dst must be wave-uniform-base + lane*16.
#define GLD_LDS16(gp, lp)                                                     \
    __builtin_amdgcn_global_load_lds(                                         \
        (const __attribute__((address_space(1))) unsigned*)(gp),              \
        (__attribute__((address_space(3))) unsigned*)(lp), 16, 0, 0)

// 32B AoS edge record: ONE random cache line per scattered edge write
struct __align__(16) ERec { int src; int dst; float cf; int pad; float4 ea; };

// Column permutation folded into weights: MFMA col c computes original col
// P(c) = (c&15)*8 + (c>>4); lane owns contiguous cols colbase*8..+7.

// ---------------- prep kernels ----------------

__global__ __launch_bounds__(128) void build_w1p_k(
    const float* __restrict__ Wb, const float* __restrict__ We1,
    const float* __restrict__ bb, const float* __restrict__ be1,
    float* __restrict__ W1p, float* __restrict__ b1p)
{
    int j = threadIdx.x;
    const float* B = We1 + 128 * 128;
    int i = blockIdx.x;
    if (i < 200) {
        float a = 0.f;
        for (int m = 0; m < 128; m++) a += Wb[i * 128 + m] * B[m * 128 + j];
        W1p[i * 128 + j] = a;
    } else {
        float a = be1[j];
        for (int m = 0; m < 128; m++) a += bb[m] * B[m * 128 + j];
        b1p[j] = a;
    }
}

// NEAREST-NEIGHBOR table, 1024 entries/channel, bf16 value only (1MB, L2-fit).
__global__ __launch_bounds__(128) void build_tab_k(
    const float* __restrict__ W1p, const float* __restrict__ b1p,
    short* __restrict__ tabN)
{
    int i = blockIdx.x;   // 0..1023
    int c = blockIdx.y;   // 0..3
    int j = threadIdx.x;
    float t = ((float)i + 0.5f) * (1.0f / 1024.0f);
    float acc = (c == 0) ? b1p[j] : 0.f;
    int kc = (int)(t * 49.f + 0.5f);
    for (int dk = -6; dk <= 6; dk++) {
        int k = kc + dk;
        if (k >= 0 && k < 50) {
            float d = t - (float)k * (1.f / 49.f);
            float g = expf(-1250.f * d * d);
            acc += g * W1p[(c * 50 + k) * 128 + j];
        }
    }
    tabN[((size_t)(c * 1024 + i)) * 128 + j] = f2bf(acc);
}

__global__ __launch_bounds__(256) void fold_plain_k(
    const float* __restrict__ W0, const float* __restrict__ W1,
    const float* __restrict__ W2, const float* __restrict__ W3,
    short* __restrict__ O0, short* __restrict__ O1,
    short* __restrict__ O2, short* __restrict__ O3)
{
    const float* W = (blockIdx.y == 0) ? W0 : (blockIdx.y == 1) ? W1 : (blockIdx.y == 2) ? W2 : W3;
    short* O = (blockIdx.y == 0) ? O0 : (blockIdx.y == 1) ? O1 : (blockIdx.y == 2) ? O2 : O3;
    int idx = blockIdx.x * 256 + threadIdx.x;
    int n = idx >> 8, ks = (idx >> 6) & 3, lane = idx & 63;
    int k8 = ks * 32 + (lane >> 4) * 8;
    int pcol = (lane & 15) * 8 + n;              // P(n*16 + colbase)
    bf16x8 fv;
    #pragma unroll
    for (int i2 = 0; i2 < 8; i2++) fv[i2] = f2bf(W[(k8 + i2) * 128 + pcol]);
    *(bf16x8*)(O + (size_t)idx * 8) = fv;
}

__global__ __launch_bounds__(256) void fold_k(
    const float* __restrict__ W, const float* __restrict__ bias,
    const float* __restrict__ statsG, const float* __restrict__ gamma,
    const float* __restrict__ beta, float invNs,
    short* __restrict__ Bp, float* __restrict__ biasOut)
{
    __shared__ float sS[128], sT[128];
    int tid = threadIdx.x;
    if (tid < 128) {
        float sum = 0.f, sq = 0.f;
        for (int r = 0; r < 16; r++) {
            sum += statsG[r * 256 + tid];
            sq  += statsG[r * 256 + 128 + tid];
        }
        float m = sum * invNs;
        float var = sq * invNs - m * m;
        float rs = rsqrtf(var + 1e-5f);
        float s = rs * gamma[tid];
        float t = beta[tid] - m * s;
        sS[tid] = s; sT[tid] = t;
    }
    __syncthreads();
    if (blockIdx.x == 0 && tid < 128) {
        float b = bias[tid];
        for (int k = 0; k < 128; k++) b += sT[k] * W[k * 128 + tid];
        biasOut[tid] = b;
    }
    int idx = blockIdx.x * 256 + tid;
    int n = idx >> 8, ks = (idx >> 6) & 3, lane = idx & 63;
    int k8 = ks * 32 + (lane >> 4) * 8;
    int pcol = (lane & 15) * 8 + n;
    bf16x8 fv;
    #pragma unroll
    for (int i2 = 0; i2 < 8; i2++)
        fv[i2] = f2bf(sS[k8 + i2] * W[(k8 + i2) * 128 + pcol]);
    *(bf16x8*)(Bp + (size_t)idx * 8) = fv;
}

// ---------------- counting sort by dst ----------------

__global__ __launch_bounds__(256) void hist_k(
    const int* __restrict__ dstI, int* __restrict__ cnt, int E)
{
    int e = blockIdx.x * 256 + threadIdx.x;
    if (e < E) atomicAdd(&cnt[dstI[e]], 1);
}

__global__ __launch_bounds__(256) void scan1_k(
    const int* __restrict__ cnt, int Nn, int* __restrict__ posE, int* __restrict__ bsum)
{
    __shared__ int s[256];
    int t = threadIdx.x, g = blockIdx.x * 256 + t;
    int v = (g < Nn) ? cnt[g] : 0;
    s[t] = v;
    __syncthreads();
    for (int off = 1; off < 256; off <<= 1) {
        int u = (t >= off) ? s[t - off] : 0;
        __syncthreads();
        s[t] += u;
        __syncthreads();
    }
    if (g < Nn) posE[g] = s[t] - v;
    if (t == 255) bsum[blockIdx.x] = s[255];
}

__global__ __launch_bounds__(256) void scan2_k(int* __restrict__ bsum, int nb)
{
    __shared__ int s[256];
    int t = threadIdx.x;
    int v = (t < nb) ? bsum[t] : 0;
    s[t] = v;
    __syncthreads();
    for (int off = 1; off < 256; off <<= 1) {
        int u = (t >= off) ? s[t - off] : 0;
        __syncthreads();
        s[t] += u;
        __syncthreads();
    }
    if (t < nb) bsum[t] = s[t] - v;
}

__global__ __launch_bounds__(256) void fix_k(
    const int* __restrict__ posE, const int* __restrict__ bsum,
    int* __restrict__ pos2, int Nn)
{
    int id = blockIdx.x * 256 + threadIdx.x;
    if (id < Nn) pos2[id] = posE[id] + bsum[id >> 8];
}

__global__ __launch_bounds__(256) void scat_k(
    const int* __restrict__ srcI, const int* __restrict__ dstI,
    const float4* __restrict__ ea4, int* __restrict__ pos2,
    ERec* __restrict__ rec, int E)
{
    int e = blockIdx.x * 256 + threadIdx.x;
    if (e >= E) return;
    int d = dstI[e];
    int p = atomicAdd(&pos2[d], 1);
    float4 ev = ea4[e];
    ERec r;
    r.src = srcI[e]; r.dst = d;
    r.cf = cosf(1.57079632679f * ev.w); r.pad = 0;
    r.ea = ev;
    rec[p] = r;    // one 32B record = one cache line (2x dwordx4 stores)
}
// NOTE: after scat_k, pos2[d] == segment END offset (start + count).

// ---------------- fused node precompute (direct-global B, small grid) ----------------
__global__ __launch_bounds__(256, 4) void node_all_k(
    const float* __restrict__ x, int M,
    const short* __restrict__ bp3,
    const float* __restrict__ bd, const float* __restrict__ vv,
    short* __restrict__ xd, short* __restrict__ zaccb,
    short* __restrict__ xs1b, short* __restrict__ xt1b)
{
    int tid = threadIdx.x;
    int wave = tid >> 6, lane = tid & 63;
    int kgrp = lane >> 4, colbase = lane & 15;
    int chunk = blockIdx.x;
    int rowA = chunk * 64 + wave * 16 + colbase;
    bool rv = rowA < M;

    bf16x8 af[4];
    #pragma unroll
    for (int ks = 0; ks < 4; ks++) {
        bf16x8 v = (bf16x8){0,0,0,0,0,0,0,0};
        if (rv) {
            const float* ap = x + (size_t)rowA * 128 + ks * 32 + kgrp * 8;
            float4 f0 = ((const float4*)ap)[0];
            float4 f1 = ((const float4*)ap)[1];
            v[0] = f2bf(f0.x); v[1] = f2bf(f0.y); v[2] = f2bf(f0.z); v[3] = f2bf(f0.w);
            v[4] = f2bf(f1.x); v[5] = f2bf(f1.y); v[6] = f2bf(f1.z); v[7] = f2bf(f1.w);
        }
        af[ks] = v;
    }

    float bcol[8], vcol[8];
    *(float4*)&bcol[0] = *(const float4*)(bd + colbase * 8);
    *(float4*)&bcol[4] = *(const float4*)(bd + colbase * 8 + 4);
    *(float4*)&vcol[0] = *(const float4*)(vv + colbase * 8);
    *(float4*)&vcol[4] = *(const float4*)(vv + colbase * 8 + 4);

    int rbase = chunk * 64 + wave * 16 + kgrp * 4;

    for (int b = 0; b < 3; b++) {
        const short* Bb = bp3 + (size_t)b * 16384;
        f32x4 acc[8];
        #pragma unroll
        for (int n = 0; n < 8; n++) acc[n] = (f32x4){0.f, 0.f, 0.f, 0.f};
        #pragma unroll
        for (int ks = 0; ks < 4; ks++) {
            #pragma unroll
            for (int n = 0; n < 8; n++) {
                bf16x8 bf = *(const bf16x8*)(Bb + ((size_t)((n * 4 + ks) * 64 + lane)) * 8);
                acc[n] = __builtin_amdgcn_mfma_f32_16x16x32_bf16(af[ks], bf, acc[n], 0, 0, 0);
            }
        }
        if (b == 0) {
            #pragma unroll
            for (int r = 0; r < 4; r++) {
                int row = rbase + r;
                if (row < M) {
                    bf16x8 xo, zo;
                    #pragma unroll
                    for (int n = 0; n < 8; n++) {
                        float val = acc[n][r] + bcol[n];
                        xo[n] = f2bf(val);
                        zo[n] = f2bf(vcol[n] * val);
                    }
                    *(bf16x8*)(xd    + (size_t)row * 128 + colbase * 8) = xo;
                    *(bf16x8*)(zaccb + (size_t)row * 128 + colbase * 8) = zo;
                }
            }
        } else {
            short* outp = (b == 1) ? xs1b : xt1b;
            #pragma unroll
            for (int r = 0; r < 4; r++) {
                int row = rbase + r;
                if (row < M) {
                    bf16x8 o;
                    #pragma unroll
                    for (int n = 0; n < 8; n++) o[n] = f2bf(acc[n][r]);
                    *(bf16x8*)(outp + (size_t)row * 128 + colbase * 8) = o;
                }
            }
        }
    }
}

// ---------------- edge pass 1: BALANCED PERSISTENT waves ---------------------
// 1024 blocks (all resident). Each wave owns a CONTIGUOUS range of quads.
// Nearest-1024 bf16 table: 1MB L2-resident footprint, no fraction math.
// lane = esub(2b) x colgroup(4b): lane handles edge q*4+esub, cols colg*8..+7

#define EZ_ISSUE(XS, XT, TT, qi) do {                                          \
    int e_ = (qi) * 4 + esub;                                                  \
    int ec_ = e_ < Etot ? e_ : Etot - 1;                                       \
    const ERec* rp_ = rec + ec_;                                               \
    int4 h_ = *(const int4*)rp_;                                               \
    float4 ea_ = *(const float4*)((const char*)rp_ + 16);                      \
    XS = *(const bf16x8*)(xs1b + (size_t)h_.x * 128 + colg * 8);               \
    XT = *(const bf16x8*)(xt1b + (size_t)h_.y * 128 + colg * 8);               \
    float tv_[4] = {ea_.x, ea_.y, ea_.z, ea_.w};                               \
    _Pragma("unroll")                                                          \
    for (int c_ = 0; c_ < 4; c_++) {                                           \
        int i0_ = (int)(tv_[c_] * 1024.f);                                     \
        i0_ = i0_ < 0 ? 0 : (i0_ > 1023 ? 1023 : i0_);                         \
        TT[c_] = *(const bf16x8*)(tabN +                                       \
            ((size_t)(c_ * 1024 + i0_) * 128) + colg * 8);                     \
    }                                                                          \
} while (0)

#define EZ_CONSUME(XS, XT, TT, qi) do {                                        \
    int e_ = (qi) * 4 + esub;                                                  \
    float p_[8];                                                               \
    _Pragma("unroll")                                                          \
    for (int j_ = 0; j_ < 8; j_++) p_[j_] = bf2f(XS[j_]) + bf2f(XT[j_]);       \
    _Pragma("unroll")                                                          \
    for (int c_ = 0; c_ < 4; c_++) {                                           \
        _Pragma("unroll")                                                      \
        for (int j_ = 0; j_ < 8; j_++) p_[j_] += bf2f(TT[c_][j_]);             \
    }                                                                          \
    bool valid_ = e_ < Etot;                                                   \
    _Pragma("unroll")                                                          \
    for (int j_ = 0; j_ < 8; j_++) {                                           \
        float z_ = p_[j_] >= 0.f ? p_[j_] : 0.01f * p_[j_];                    \
        p_[j_] = z_;                                                           \
        float m_ = valid_ ? z_ : 0.f;                                          \
        sacc[j_] += m_;                                                        \
        qacc[j_] = fmaf(m_, z_, qacc[j_]);                                     \
    }                                                                          \
    if (valid_) {                                                              \
        uint32x4 ov_ = {pkbf(p_[0], p_[1]), pkbf(p_[2], p_[3]),                \
                        pkbf(p_[4], p_[5]), pkbf(p_[6], p_[7])};               \
        *(uint32x4*)(z1 + (size_t)e_ * 128 + colg * 8) = ov_;                  \
    }                                                                          \
} while (0)

__global__ __launch_bounds__(256) void edge_z1_k(
    const short* __restrict__ xs1b, const short* __restrict__ xt1b,
    const short* __restrict__ tabN,
    const ERec* __restrict__ rec,
    short* __restrict__ z1, float* __restrict__ stats, int Etot)
{
    int tid = threadIdx.x, wave = tid >> 6, lane = tid & 63;
    int colg = lane & 15, esub = lane >> 4;

    int gw = blockIdx.x * 4 + wave;          // global wave id
    int W = gridDim.x * 4;                   // total waves
    int nq = (Etot + 3) >> 2;                // total 4-edge quads
    int q0 = (int)(((long long)gw * nq) / W);
    int q1 = (int)(((long long)(gw + 1) * nq) / W);
    int nsteps = q1 - q0;                    // balanced to +-1

    float sacc[8], qacc[8];
    #pragma unroll
    for (int j = 0; j < 8; j++) { sacc[j] = 0.f; qacc[j] = 0.f; }

    bf16x8 xsA, xtA, ttA[4];
    bf16x8 xsB, xtB, ttB[4];
    bf16x8 xsC, xtC, ttC[4];

    if (nsteps > 0) {
        EZ_ISSUE(xsA, xtA, ttA, q0 + 0);
        EZ_ISSUE(xsB, xtB, ttB, q0 + 1);     // clamped if overshoot
        int st = 0;
        for (; st + 3 <= nsteps; st += 3) {
            EZ_ISSUE(xsC, xtC, ttC, q0 + st + 2);
            EZ_CONSUME(xsA, xtA, ttA, q0 + st);
            EZ_ISSUE(xsA, xtA, ttA, q0 + st + 3);
            EZ_CONSUME(xsB, xtB, ttB, q0 + st + 1);
            EZ_ISSUE(xsB, xtB, ttB, q0 + st + 4);
            EZ_CONSUME(xsC, xtC, ttC, q0 + st + 2);
        }
        if (st < nsteps)
            EZ_CONSUME(xsA, xtA, ttA, q0 + st);
        if (st + 1 < nsteps)
            EZ_CONSUME(xsB, xtB, ttB, q0 + st + 1);
    }

    // pre-reduce across the 4 esub lanes sharing a column group (lanes
    // colg, colg+16, colg+32, colg+48) -> 4x fewer LDS atomics
    #pragma unroll
    for (int j = 0; j < 8; j++) {
        sacc[j] += __shfl_xor(sacc[j], 16);
        sacc[j] += __shfl_xor(sacc[j], 32);
        qacc[j] += __shfl_xor(qacc[j], 16);
        qacc[j] += __shfl_xor(qacc[j], 32);
    }

    __shared__ float lS[128], lQ[128];
    if (tid < 128) { lS[tid] = 0.f; lQ[tid] = 0.f; }
    __syncthreads();
    if (esub == 0) {
        #pragma unroll
        for (int j = 0; j < 8; j++) {
            atomicAdd(&lS[colg * 8 + j], sacc[j]);
            atomicAdd(&lQ[colg * 8 + j], qacc[j]);
        }
    }
    __syncthreads();
    if (tid < 128) {
        int rep = blockIdx.x & 15;
        atomicAdd(&stats[rep * 256 + tid], lS[tid]);
        atomicAdd(&stats[rep * 256 + 128 + tid], lQ[tid]);
    }
}

// ---------------- segmented reduce over dst-sorted edges (no atomics) ----
// 8 dsts/wave: doubles wave count -> keeps SIMDs fed through drain.
__global__ __launch_bounds__(256) void segred_k(
    const short* __restrict__ cond, const short* __restrict__ xd,
    const ERec* __restrict__ rec, const int* __restrict__ endPos,
    short* __restrict__ zaccb, int Nn)
{
    int tid = threadIdx.x, wave = tid >> 6, lane = tid & 63;
    int colg = lane & 7;        // 8 col-groups x 16 cols
    int esub = lane >> 3;       // 8 edges in parallel
    int d0 = blockIdx.x * 32 + wave * 8;

    for (int i = 0; i < 8; i++) {
        int d = d0 + i;
        if (d >= Nn) break;
        int s0 = (d == 0) ? 0 : endPos[d - 1];
        int s1 = endPos[d];
        if (s1 <= s0) continue;            // empty segment: zaccb already = m_t

        float acc[16];
        #pragma unroll
        for (int j = 0; j < 16; j++) acc[j] = 0.f;

        for (int t = s0 + esub; t < s1; t += 8) {
            const short* cp = cond + (size_t)t * 128 + colg * 16;
            bf16x8 c0 = *(const bf16x8*)cp;
            bf16x8 c1 = *(const bf16x8*)(cp + 8);
            int s = rec[t].src;
            const short* xp = xd + (size_t)s * 128 + colg * 16;
            bf16x8 x0 = *(const bf16x8*)xp;
            bf16x8 x1 = *(const bf16x8*)(xp + 8);
            #pragma unroll
            for (int j = 0; j < 8; j++) {
                acc[j]     += bf2f(c0[j]) * bf2f(x0[j]);
                acc[8 + j] += bf2f(c1[j]) * bf2f(x1[j]);
            }
        }

        #pragma unroll
        for (int j = 0; j < 16; j++) {
            acc[j] += __shfl_xor(acc[j], 8);
            acc[j] += __shfl_xor(acc[j], 16);
            acc[j] += __shfl_xor(acc[j], 32);
        }

        if (esub == 0) {
            short* zp = zaccb + (size_t)d * 128 + colg * 16;
            bf16x8 z0 = *(const bf16x8*)zp;
            bf16x8 z1 = *(const bf16x8*)(zp + 8);
            bf16x8 o0, o1;
            #pragma unroll
            for (int j = 0; j < 8; j++) {
                o0[j] = f2bf(bf2f(z0[j]) + acc[j]);
                o1[j] = f2bf(bf2f(z1[j]) + acc[8 + j]);
            }
            *(bf16x8*)zp = o0;
            *(bf16x8*)(zp + 8) = o1;
        }
    }
}

// ---------------- persistent MFMA GEMM, balanced ranges, unroll-2 A pipeline --
// (R12's in-prologue fold REVERTED: 1024x redundant Wf reads + LDS conflicts
//  cost far more than the 3 fold_k dispatches it removed. R11 structure.)
// Register-diet epilogues vs R11 (fix for VGPR=128 spill): no zz_[] temp
// array (pair-wise pkbf immediately), EPI3 cf read at epilogue time.
// EPI 2: z=lrelu(val); out bf16; BN stats
// EPI 3: out bf16 = rec[row].cf * val   (cond_filter, in-place over A)
// EPI 4: out fp32 = val + xres

#define PG_LOADA(AF, ci) do {                                                  \
    int rowA_ = (ci) * 64 + wave * 16 + colbase;                               \
    bool rv_ = ((ci) < cend) && (rowA_ < M);                                   \
    _Pragma("unroll")                                                          \
    for (int ks_ = 0; ks_ < 4; ks_++)                                          \
        AF[ks_] = rv_ ? *(const bf16x8*)(A + (size_t)rowA_ * 128 + ks_ * 32 + kgrp * 8) \
                      : (bf16x8){0,0,0,0,0,0,0,0};                             \
} while (0)

#define PG_PROC(AF, ci) do {                                                   \
    int rbase_ = (ci) * 64 + wave * 16 + kgrp * 4;                             \
    f32x4 acc_[8];                                                             \
    _Pragma("unroll")                                                          \
    for (int n_ = 0; n_ < 8; n_++) acc_[n_] = (f32x4){0.f, 0.f, 0.f, 0.f};     \
    _Pragma("unroll")                                                          \
    for (int ks_ = 0; ks_ < 4; ks_++) {                                        \
        _Pragma("unroll")                                                      \
        for (int n_ = 0; n_ < 8; n_++) {                                       \
            bf16x8 bf_ = *(const bf16x8*)(ldsB + ((size_t)((n_ * 4 + ks_) * 64 + lane)) * 8); \
            acc_[n_] = __builtin_amdgcn_mfma_f32_16x16x32_bf16(AF[ks_], bf_, acc_[n_], 0, 0, 0); \
        }                                                                      \
    }                                                                          \
    if (EPI == 2) {                                                            \
        short* outh_ = (short*)out;                                            \
        _Pragma("unroll")                                                      \
        for (int r_ = 0; r_ < 4; r_++) {                                       \
            int row_ = rbase_ + r_;                                            \
            uint32x4 ov_;                                                      \
            _Pragma("unroll")                                                  \
            for (int q_ = 0; q_ < 4; q_++) {                                   \
                float za_ = acc_[2 * q_][r_] + bcol[2 * q_];                   \
                za_ = za_ >= 0.f ? za_ : 0.01f * za_;                          \
                float zb_ = acc_[2 * q_ + 1][r_] + bcol[2 * q_ + 1];           \
                zb_ = zb_ >= 0.f ? zb_ : 0.01f * zb_;                          \
                if (row_ >= M) { za_ = 0.f; zb_ = 0.f; }                       \
                sreg[2 * q_] += za_;     qreg[2 * q_] += za_ * za_;            \
                sreg[2 * q_ + 1] += zb_; qreg[2 * q_ + 1] += zb_ * zb_;        \
                ov_[q_] = pkbf(za_, zb_);                                      \
            }                                                                  \
            if (row_ < M)                                                      \
                *(uint32x4*)(outh_ + (size_t)row_ * 128 + colbase * 8) = ov_;  \
        }                                                                      \
    } else if (EPI == 3) {                                                     \
        short* outh_ = (short*)out;                                            \
        _Pragma("unroll")                                                      \
        for (int r_ = 0; r_ < 4; r_++) {                                       \
            int row_ = rbase_ + r_;                                            \
            if (row_ < M) {                                                    \
                float cfv_ = rec[row_].cf;                                     \
                uint32x4 ov_;                                                  \
                _Pragma("unroll")                                              \
                for (int q_ = 0; q_ < 4; q_++)                                 \
                    ov_[q_] = pkbf(cfv_ * (acc_[2 * q_][r_] + bcol[2 * q_]),   \
                                   cfv_ * (acc_[2 * q_ + 1][r_] + bcol[2 * q_ + 1])); \
                *(uint32x4*)(outh_ + (size_t)row_ * 128 + colbase * 8) = ov_;  \
            }                                                                  \
        }                                                                      \
    } else if (EPI == 4) {                                                     \
        float* outf_ = (float*)out;                                            \
        _Pragma("unroll")                                                      \
        for (int r_ = 0; r_ < 4; r_++) {                                       \
            int row_ = rbase_ + r_;                                            \
            if (row_ < M) {                                                    \
                const float4* xr_ = (const float4*)(xres + (size_t)row_ * 128 + colbase * 8); \
                float4 x0_ = xr_[0], x1_ = xr_[1];                             \
                float4 o0_, o1_;                                               \
                o0_.x = acc_[0][r_] + bcol[0] + x0_.x;                         \
                o0_.y = acc_[1][r_] + bcol[1] + x0_.y;                         \
                o0_.z = acc_[2][r_] + bcol[2] + x0_.z;                         \
                o0_.w = acc_[3][r_] + bcol[3] + x0_.w;                         \
                o1_.x = acc_[4][r_] + bcol[4] + x1_.x;                         \
                o1_.y = acc_[5][r_] + bcol[5] + x1_.y;                         \
                o1_.z = acc_[6][r_] + bcol[6] + x1_.z;                         \
                o1_.w = acc_[7][r_] + bcol[7] + x1_.w;                         \
                float4* op_ = (float4*)(outf_ + (size_t)row_ * 128 + colbase * 8); \
                op_[0] = o0_; op_[1] = o1_;                                    \
            }                                                                  \
        }                                                                      \
    }                                                                          \
} while (0)

template<int EPI>
__global__ __launch_bounds__(256, 2) void pgemm_k(
    const short* __restrict__ A, int M,
    const short* __restrict__ Bp, const float* __restrict__ bias,
    void* __restrict__ out, float* __restrict__ stats,
    const ERec* __restrict__ rec, const float* __restrict__ xres)
{
    __shared__ __align__(16) short ldsB[16384];
    __shared__ float lS[128], lQ[128];
    int tid = threadIdx.x;
    int wave = tid >> 6, lane = tid & 63;
    int kgrp = lane >> 4, colbase = lane & 15;

    // async stage B -> LDS once: 8 issues x (4 waves x 64 lanes x 16B) = 32KB
    #pragma unroll
    for (int i = 0; i < 8; i++) {
        int off = (i * 256 + wave * 64 + lane) * 8;   // shorts; lane-contiguous
        GLD_LDS16(Bp + off, ldsB + off);
    }

    int nch = (M + 63) >> 6;
    // balanced contiguous chunk range for this block
    int cbeg = (int)(((long long)blockIdx.x * nch) / gridDim.x);
    int cend = (int)(((long long)(blockIdx.x + 1) * nch) / gridDim.x);

    // prologue: A fragments for the first two chunks
    bf16x8 afA[4], afB[4];
    PG_LOADA(afA, cbeg);
    PG_LOADA(afB, cbeg + 1);

    float bcol[8];
    *(float4*)&bcol[0] = *(const float4*)(bias + colbase * 8);
    *(float4*)&bcol[4] = *(const float4*)(bias + colbase * 8 + 4);

    float sreg[8], qreg[8];
    if (EPI == 2) {
        #pragma unroll
        for (int n = 0; n < 8; n++) { sreg[n] = 0.f; qreg[n] = 0.f; }
        if (tid < 128) { lS[tid] = 0.f; lQ[tid] = 0.f; }
    }

    __syncthreads();   // B staged (once per block for the whole dispatch)

    int c = cbeg;
    for (; c + 1 < cend; c += 2) {
        PG_PROC(afA, c);            // consume afA (loads issued 2 chunks ago)
        PG_LOADA(afA, c + 2);       // refill AFTER consumption: 2-chunk lead
        PG_PROC(afB, c + 1);
        PG_LOADA(afB, c + 3);
    }
    if (c < cend)
        PG_PROC(afA, c);            // odd tail

    if (EPI == 2) {
        // pre-reduce across the 4 kgrp lanes sharing colbase -> 4x fewer atomics
        #pragma unroll
        for (int n = 0; n < 8; n++) {
            sreg[n] += __shfl_xor(sreg[n], 16);
            sreg[n] += __shfl_xor(sreg[n], 32);
            qreg[n] += __shfl_xor(qreg[n], 16);
            qreg[n] += __shfl_xor(qreg[n], 32);
        }
        __syncthreads();
        if (kgrp == 0) {
            #pragma unroll
            for (int n = 0; n < 8; n++) {
                atomicAdd(&lS[colbase * 8 + n], sreg[n]);
                atomicAdd(&lQ[colbase * 8 + n], qreg[n]);
            }
        }
        __syncthreads();
        if (tid < 128) {
            int rep = blockIdx.x & 15;
            atomicAdd(&stats[rep * 256 + tid], lS[tid]);
            atomicAdd(&stats[rep * 256 + 128 + tid], lQ[tid]);
        }
    }
}

extern "C" void kernel_launch(void* const* d_in, const int* in_sizes, int n_in,
                              void* d_out, int out_size, void* d_ws, size_t ws_size,
                              hipStream_t stream)
{
    const float* x    = (const float*)d_in[0];
    const float* ea   = (const float*)d_in[1];
    const int*   eidx = (const int*)d_in[2];
    const float* Wb   = (const float*)d_in[3];
    const float* bb   = (const float*)d_in[4];
    const float* We1  = (const float*)d_in[5];
    const float* be1  = (const float*)d_in[6];
    const float* ge1  = (const float*)d_in[7];
    const float* bte1 = (const float*)d_in[8];
    const float* We2  = (const float*)d_in[9];
    const float* be2  = (const float*)d_in[10];
    const float* ge2  = (const float*)d_in[11];
    const float* bte2 = (const float*)d_in[12];
    const float* We3  = (const float*)d_in[13];
    const float* be3  = (const float*)d_in[14];
    const float* Wd   = (const float*)d_in[15];
    const float* bd   = (const float*)d_in[16];
    const float* vv   = (const float*)d_in[17];
    const float* Wn1  = (const float*)d_in[18];
    const float* bn1  = (const float*)d_in[19];
    const float* gn   = (const float*)d_in[20];
    const float* btn  = (const float*)d_in[21];
    const float* Wn2  = (const float*)d_in[22];
    const float* bn2  = (const float*)d_in[23];

    const int NN = in_sizes[0] / 128;   // 50000
    const int EE = in_sizes[1] / 4;     // 300000

    char* ws = (char*)d_ws;
    size_t oEZ   = 0;
    size_t oXD   = oEZ   + (size_t)EE * 256;
    size_t oXS   = oXD   + (size_t)NN * 256;
    size_t oXT   = oXS   + (size_t)NN * 256;
    size_t oZACC = oXT   + (size_t)NN * 256;
    size_t oZN   = oZACC + (size_t)NN * 256;
    size_t oTAB  = oZN   + (size_t)NN * 256;
    size_t oW1P  = oTAB  + (size_t)4 * 1024 * 256;   // nearest table: 1MB
    size_t oB1P  = oW1P  + (size_t)200 * 512;
    size_t oBP   = oB1P  + 512;
    size_t oBIAS = oBP   + (size_t)7 * 32768;
    size_t oST   = oBIAS + (size_t)7 * 512;
    size_t oCNT  = oST   + 49152;
    size_t oPOS  = oCNT  + 201728;
    size_t oBSUM = oPOS  + 201728;
    size_t oPOS2 = oBSUM + 1024;
    size_t oREC  = (oPOS2 + 201728 + 31) & ~(size_t)31;   // EE x 32B records

    short* eZ    = (short*)(ws + oEZ);
    short* xd    = (short*)(ws + oXD);
    short* xs1b  = (short*)(ws + oXS);
    short* xt1b  = (short*)(ws + oXT);
    short* zaccb = (short*)(ws + oZACC);
    short* zn    = (short*)(ws + oZN);
    short* tabN  = (short*)(ws + oTAB);
    float* W1p   = (float*)(ws + oW1P);
    float* b1p   = (float*)(ws + oB1P);
    short* bp    = (short*)(ws + oBP);
    short* BpW2  = bp + 3 * 16384;
    short* BpW3  = bp + 4 * 16384;
    short* BpN1  = bp + 5 * 16384;
    short* BpN2  = bp + 6 * 16384;
    float* bo    = (float*)(ws + oBIAS);
    float* b2p   = bo + 0 * 128;
    float* b3p   = bo + 1 * 128;
    float* b2np  = bo + 2 * 128;
    float* st1   = (float*)(ws + oST);
    float* st2   = st1 + 4096;
    float* stN   = st1 + 8192;
    int*   cnt   = (int*)(ws + oCNT);
    int*   posE  = (int*)(ws + oPOS);
    int*   bsum  = (int*)(ws + oBSUM);
    int*   pos2  = (int*)(ws + oPOS2);
    ERec*  rec   = (ERec*)(ws + oREC);

    hipMemsetAsync(ws + oST, 0, 49152 + 201728, stream);

    build_w1p_k<<<201, 128, 0, stream>>>(Wb, We1, bb, be1, W1p, b1p);
    build_tab_k<<<dim3(1024, 4), 128, 0, stream>>>(W1p, b1p, tabN);
    fold_plain_k<<<dim3(8, 4), 256, 0, stream>>>(
        Wd, We1, We1 + 256 * 128, Wn1, bp, bp + 16384, bp + 2 * 16384, BpN1);

    int nchN = (NN + 63) / 64;
    int nchE = (EE + 63) / 64;
    int nbN = (NN + 255) / 256;
    int nbE = (EE + 255) / 256;
    int nbSeg = (NN + 31) / 32;         // segred: 32 dsts/block (8/wave)

    // persistent grids: at most the resident capacity (4 blocks/CU x 256 CU)
    int gridEz = 1024;
    int gridE = nchE < 1024 ? nchE : 1024;
    int gridN = nchN < 1024 ? nchN : 1024;   // 782: exactly 1 chunk/block

    // fused node precompute: xd/zacc, xs1, xt1  (reads x once)
    node_all_k<<<nchN, 256, 0, stream>>>(x, NN, bp, bd, vv, xd, zaccb, xs1b, xt1b);

    // counting sort by dst
    hist_k<<<nbE, 256, 0, stream>>>(eidx + EE, cnt, EE);
    scan1_k<<<nbN, 256, 0, stream>>>(cnt, NN, posE, bsum);
    scan2_k<<<1, 256, 0, stream>>>(bsum, nbN);
    fix_k<<<nbN, 256, 0, stream>>>(posE, bsum, pos2, NN);
    scat_k<<<nbE, 256, 0, stream>>>(eidx, eidx + EE, (const float4*)ea, pos2,
                                    rec, EE);

    edge_z1_k<<<gridEz, 256, 0, stream>>>(xs1b, xt1b, tabN, rec, eZ, st1, EE);

    fold_k<<<8, 256, 0, stream>>>(We2, be2, st1, ge1, bte1, 1.f / (float)EE, BpW2, b2p);
    pgemm_k<2><<<gridE, 256, 0, stream>>>(eZ, EE, BpW2, b2p, eZ, st2,
        nullptr, nullptr);

    fold_k<<<8, 256, 0, stream>>>(We3, be3, st2, ge2, bte2, 1.f / (float)EE, BpW3, b3p);
    // cond_filter = cf * (z2 @ W3f + b3), written in-place over eZ
    pgemm_k<3><<<gridE, 256, 0, stream>>>(eZ, EE, BpW3, b3p, eZ, nullptr,
        rec, nullptr);

    // segmented reduction (dst-sorted, pos2 = segment end offsets): zaccb += sum cond*xd[src]
    segred_k<<<nbSeg, 256, 0, stream>>>(eZ, xd, rec, pos2, zaccb, NN);

    pgemm_k<2><<<gridN, 256, 0, stream>>>(zaccb, NN, BpN1, bn1, zn, stN,
        nullptr, nullptr);

    fold_k<<<8, 256, 0, stream>>>(Wn2, bn2, stN, gn, btn, 1.f / (float)NN, BpN2, b2np);
    pgemm_k<4><<<gridN, 256, 0, stream>>>(zn, NN, BpN2, b2np, d_out, nullptr,
        nullptr, x);
}

// Round 14
// 380.217 us; speedup vs baseline: 1.2366x; 1.0104x over previous
//
#include <hip/hip_runtime.h>

typedef __attribute__((ext_vector_type(8))) short bf16x8;
typedef __attribute__((ext_vector_type(4))) float f32x4;
typedef __attribute__((ext_vector_type(4))) unsigned uint32x4;

#define DEVFN __device__ __forceinline__

DEVFN short f2bf(float f) {
    union { float f; unsigned u; } v; v.f = f;
    unsigned r = (v.u + 0x7FFFu + ((v.u >> 16) & 1u)) >> 16;
    return (short)(unsigned short)r;
}
DEVFN float bf2f(short h) {
    union { unsigned u; float f; } v; v.u = ((unsigned)(unsigned short)h) << 16;
    return v.f;
}
// HW packed f32->bf16 (RNE, same as f2bf): 1 inst per 2 values
DEVFN unsigned pkbf(float a, float b) {
    unsigned r;
    asm("v_cvt_pk_bf16_f32 %0, %1, %2" : "=v"(r) : "v"(a), "v"(b));
    return r;
}

// async global->LDS, 16B per lane. lds dst must be wave-uniform-base + lane*16.
#define GLD_LDS16(gp, lp)                                                     \
    __builtin_amdgcn_global_load_lds(                                         \
        (const __attribute__((address_space(1))) unsigned*)(gp),              \
        (__attribute__((address_space(3))) unsigned*)(lp), 16, 0, 0)

// 32B AoS edge record: ONE random cache line per scattered edge write
struct __align__(16) ERec { int src; int dst; float cf; int pad; float4 ea; };

// Column permutation folded into weights: MFMA col c computes original col
// P(c) = (c&15)*8 + (c>>4); lane owns contiguous cols colbase*8..+7.

// ---------------- merged prep: build_w1p (blocks 0..200) + fold_plain (201..232)
__global__ __launch_bounds__(256) void prep_k(
    const float* __restrict__ Wb, const float* __restrict__ We1,
    const float* __restrict__ bb, const float* __restrict__ be1,
    float* __restrict__ W1p, float* __restrict__ b1p,
    const float* __restrict__ W0, const float* __restrict__ W1,
    const float* __restrict__ W2, const float* __restrict__ W3,
    short* __restrict__ O0, short* __restrict__ O1,
    short* __restrict__ O2, short* __restrict__ O3)
{
    int bx = blockIdx.x;
    if (bx < 201) {
        if (threadIdx.x >= 128) return;
        int j = threadIdx.x;
        const float* B = We1 + 128 * 128;
        int i = bx;
        if (i < 200) {
            float a = 0.f;
            for (int m = 0; m < 128; m++) a += Wb[i * 128 + m] * B[m * 128 + j];
            W1p[i * 128 + j] = a;
        } else {
            float a = be1[j];
            for (int m = 0; m < 128; m++) a += bb[m] * B[m * 128 + j];
            b1p[j] = a;
        }
    } else {
        int fb = bx - 201;          // 0..31
        int fx = fb & 7;            // fold_plain blockIdx.x
        int fy = fb >> 3;           // fold_plain blockIdx.y
        const float* W = (fy == 0) ? W0 : (fy == 1) ? W1 : (fy == 2) ? W2 : W3;
        short* O = (fy == 0) ? O0 : (fy == 1) ? O1 : (fy == 2) ? O2 : O3;
        int idx = fx * 256 + threadIdx.x;
        int n = idx >> 8, ks = (idx >> 6) & 3, lane = idx & 63;
        int k8 = ks * 32 + (lane >> 4) * 8;
        int pcol = (lane & 15) * 8 + n;              // P(n*16 + colbase)
        bf16x8 fv;
        #pragma unroll
        for (int i2 = 0; i2 < 8; i2++) fv[i2] = f2bf(W[(k8 + i2) * 128 + pcol]);
        *(bf16x8*)(O + (size_t)idx * 8) = fv;
    }
}

// NEAREST-NEIGHBOR table, 1024 entries/channel, bf16 value only (1MB, L2-fit).
__global__ __launch_bounds__(128) void build_tab_k(
    const float* __restrict__ W1p, const float* __restrict__ b1p,
    short* __restrict__ tabN)
{
    int i = blockIdx.x;   // 0..1023
    int c = blockIdx.y;   // 0..3
    int j = threadIdx.x;
    float t = ((float)i + 0.5f) * (1.0f / 1024.0f);
    float acc = (c == 0) ? b1p[j] : 0.f;
    int kc = (int)(t * 49.f + 0.5f);
    for (int dk = -6; dk <= 6; dk++) {
        int k = kc + dk;
        if (k >= 0 && k < 50) {
            float d = t - (float)k * (1.f / 49.f);
            float g = expf(-1250.f * d * d);
            acc += g * W1p[(c * 50 + k) * 128 + j];
        }
    }
    tabN[((size_t)(c * 1024 + i)) * 128 + j] = f2bf(acc);
}

__global__ __launch_bounds__(256) void fold_k(
    const float* __restrict__ W, const float* __restrict__ bias,
    const float* __restrict__ statsG, const float* __restrict__ gamma,
    const float* __restrict__ beta, float invNs,
    short* __restrict__ Bp, float* __restrict__ biasOut)
{
    __shared__ float sS[128], sT[128];
    int tid = threadIdx.x;
    if (tid < 128) {
        float sum = 0.f, sq = 0.f;
        for (int r = 0; r < 16; r++) {
            sum += statsG[r * 256 + tid];
            sq  += statsG[r * 256 + 128 + tid];
        }
        float m = sum * invNs;
        float var = sq * invNs - m * m;
        float rs = rsqrtf(var + 1e-5f);
        float s = rs * gamma[tid];
        float t = beta[tid] - m * s;
        sS[tid] = s; sT[tid] = t;
    }
    __syncthreads();
    if (blockIdx.x == 0 && tid < 128) {
        float b = bias[tid];
        for (int k = 0; k < 128; k++) b += sT[k] * W[k * 128 + tid];
        biasOut[tid] = b;
    }
    int idx = blockIdx.x * 256 + tid;
    int n = idx >> 8, ks = (idx >> 6) & 3, lane = idx & 63;
    int k8 = ks * 32 + (lane >> 4) * 8;
    int pcol = (lane & 15) * 8 + n;
    bf16x8 fv;
    #pragma unroll
    for (int i2 = 0; i2 < 8; i2++)
        fv[i2] = f2bf(sS[k8 + i2] * W[(k8 + i2) * 128 + pcol]);
    *(bf16x8*)(Bp + (size_t)idx * 8) = fv;
}

// ---------------- counting sort by dst ----------------

__global__ __launch_bounds__(256) void hist_k(
    const int* __restrict__ dstI, int* __restrict__ cnt, int E)
{
    int e = blockIdx.x * 256 + threadIdx.x;
    if (e < E) atomicAdd(&cnt[dstI[e]], 1);
}

__global__ __launch_bounds__(256) void scan1_k(
    const int* __restrict__ cnt, int Nn, int* __restrict__ posE, int* __restrict__ bsum)
{
    __shared__ int s[256];
    int t = threadIdx.x, g = blockIdx.x * 256 + t;
    int v = (g < Nn) ? cnt[g] : 0;
    s[t] = v;
    __syncthreads();
    for (int off = 1; off < 256; off <<= 1) {
        int u = (t >= off) ? s[t - off] : 0;
        __syncthreads();
        s[t] += u;
        __syncthreads();
    }
    if (g < Nn) posE[g] = s[t] - v;
    if (t == 255) bsum[blockIdx.x] = s[255];
}

__global__ __launch_bounds__(256) void scan2_k(int* __restrict__ bsum, int nb)
{
    __shared__ int s[256];
    int t = threadIdx.x;
    int v = (t < nb) ? bsum[t] : 0;
    s[t] = v;
    __syncthreads();
    for (int off = 1; off < 256; off <<= 1) {
        int u = (t >= off) ? s[t - off] : 0;
        __syncthreads();
        s[t] += u;
        __syncthreads();
    }
    if (t < nb) bsum[t] = s[t] - v;
}

// scat: start offset computed inline (posE + bsum-prefix) + per-dst running
// counter in cnt2 (zeroed by the memset). fix_k eliminated.
__global__ __launch_bounds__(256) void scat_k(
    const int* __restrict__ srcI, const int* __restrict__ dstI,
    const float4* __restrict__ ea4,
    const int* __restrict__ posE, const int* __restrict__ bsum,
    int* __restrict__ cnt2,
    ERec* __restrict__ rec, int E)
{
    int e = blockIdx.x * 256 + threadIdx.x;
    if (e >= E) return;
    int d = dstI[e];
    int p = posE[d] + bsum[d >> 8] + atomicAdd(&cnt2[d], 1);
    float4 ev = ea4[e];
    ERec r;
    r.src = srcI[e]; r.dst = d;
    r.cf = cosf(1.57079632679f * ev.w); r.pad = 0;
    r.ea = ev;
    rec[p] = r;    // one 32B record = one cache line (2x dwordx4 stores)
}

// ---------------- fused node precompute (direct-global B, small grid) ----------------
__global__ __launch_bounds__(256, 4) void node_all_k(
    const float* __restrict__ x, int M,
    const short* __restrict__ bp3,
    const float* __restrict__ bd, const float* __restrict__ vv,
    short* __restrict__ xd, short* __restrict__ zaccb,
    short* __restrict__ xs1b, short* __restrict__ xt1b)
{
    int tid = threadIdx.x;
    int wave = tid >> 6, lane = tid & 63;
    int kgrp = lane >> 4, colbase = lane & 15;
    int chunk = blockIdx.x;
    int rowA = chunk * 64 + wave * 16 + colbase;
    bool rv = rowA < M;

    bf16x8 af[4];
    #pragma unroll
    for (int ks = 0; ks < 4; ks++) {
        bf16x8 v = (bf16x8){0,0,0,0,0,0,0,0};
        if (rv) {
            const float* ap = x + (size_t)rowA * 128 + ks * 32 + kgrp * 8;
            float4 f0 = ((const float4*)ap)[0];
            float4 f1 = ((const float4*)ap)[1];
            v[0] = f2bf(f0.x); v[1] = f2bf(f0.y); v[2] = f2bf(f0.z); v[3] = f2bf(f0.w);
            v[4] = f2bf(f1.x); v[5] = f2bf(f1.y); v[6] = f2bf(f1.z); v[7] = f2bf(f1.w);
        }
        af[ks] = v;
    }

    float bcol[8], vcol[8];
    *(float4*)&bcol[0] = *(const float4*)(bd + colbase * 8);
    *(float4*)&bcol[4] = *(const float4*)(bd + colbase * 8 + 4);
    *(float4*)&vcol[0] = *(const float4*)(vv + colbase * 8);
    *(float4*)&vcol[4] = *(const float4*)(vv + colbase * 8 + 4);

    int rbase = chunk * 64 + wave * 16 + kgrp * 4;

    for (int b = 0; b < 3; b++) {
        const short* Bb = bp3 + (size_t)b * 16384;
        f32x4 acc[8];
        #pragma unroll
        for (int n = 0; n < 8; n++) acc[n] = (f32x4){0.f, 0.f, 0.f, 0.f};
        #pragma unroll
        for (int ks = 0; ks < 4; ks++) {
            #pragma unroll
            for (int n = 0; n < 8; n++) {
                bf16x8 bf = *(const bf16x8*)(Bb + ((size_t)((n * 4 + ks) * 64 + lane)) * 8);
                acc[n] = __builtin_amdgcn_mfma_f32_16x16x32_bf16(af[ks], bf, acc[n], 0, 0, 0);
            }
        }
        if (b == 0) {
            #pragma unroll
            for (int r = 0; r < 4; r++) {
                int row = rbase + r;
                if (row < M) {
                    bf16x8 xo, zo;
                    #pragma unroll
                    for (int n = 0; n < 8; n++) {
                        float val = acc[n][r] + bcol[n];
                        xo[n] = f2bf(val);
                        zo[n] = f2bf(vcol[n] * val);
                    }
                    *(bf16x8*)(xd    + (size_t)row * 128 + colbase * 8) = xo;
                    *(bf16x8*)(zaccb + (size_t)row * 128 + colbase * 8) = zo;
                }
            }
        } else {
            short* outp = (b == 1) ? xs1b : xt1b;
            #pragma unroll
            for (int r = 0; r < 4; r++) {
                int row = rbase + r;
                if (row < M) {
                    bf16x8 o;
                    #pragma unroll
                    for (int n = 0; n < 8; n++) o[n] = f2bf(acc[n][r]);
                    *(bf16x8*)(outp + (size_t)row * 128 + colbase * 8) = o;
                }
            }
        }
    }
}

// ---------------- edge pass 1: BALANCED PERSISTENT waves ---------------------
// 1024 blocks (all resident). Each wave owns a CONTIGUOUS range of quads.
// Nearest-1024 bf16 table: 1MB L2-resident footprint, no fraction math.
// lane = esub(2b) x colgroup(4b): lane handles edge q*4+esub, cols colg*8..+7

#define EZ_ISSUE(XS, XT, TT, qi) do {                                          \
    int e_ = (qi) * 4 + esub;                                                  \
    int ec_ = e_ < Etot ? e_ : Etot - 1;                                       \
    const ERec* rp_ = rec + ec_;                                               \
    int4 h_ = *(const int4*)rp_;                                               \
    float4 ea_ = *(const float4*)((const char*)rp_ + 16);                      \
    XS = *(const bf16x8*)(xs1b + (size_t)h_.x * 128 + colg * 8);               \
    XT = *(const bf16x8*)(xt1b + (size_t)h_.y * 128 + colg * 8);               \
    float tv_[4] = {ea_.x, ea_.y, ea_.z, ea_.w};                               \
    _Pragma("unroll")                                                          \
    for (int c_ = 0; c_ < 4; c_++) {                                           \
        int i0_ = (int)(tv_[c_] * 1024.f);                                     \
        i0_ = i0_ < 0 ? 0 : (i0_ > 1023 ? 1023 : i0_);                         \
        TT[c_] = *(const bf16x8*)(tabN +                                       \
            ((size_t)(c_ * 1024 + i0_) * 128) + colg * 8);                     \
    }                                                                          \
} while (0)

#define EZ_CONSUME(XS, XT, TT, qi) do {                                        \
    int e_ = (qi) * 4 + esub;                                                  \
    float p_[8];                                                               \
    _Pragma("unroll")                                                          \
    for (int j_ = 0; j_ < 8; j_++) p_[j_] = bf2f(XS[j_]) + bf2f(XT[j_]);       \
    _Pragma("unroll")                                                          \
    for (int c_ = 0; c_ < 4; c_++) {                                           \
        _Pragma("unroll")                                                      \
        for (int j_ = 0; j_ < 8; j_++) p_[j_] += bf2f(TT[c_][j_]);             \
    }                                                                          \
    bool valid_ = e_ < Etot;                                                   \
    _Pragma("unroll")                                                          \
    for (int j_ = 0; j_ < 8; j_++) {                                           \
        float z_ = p_[j_] >= 0.f ? p_[j_] : 0.01f * p_[j_];                    \
        p_[j_] = z_;                                                           \
        float m_ = valid_ ? z_ : 0.f;                                          \
        sacc[j_] += m_;                                                        \
        qacc[j_] = fmaf(m_, z_, qacc[j_]);                                     \
    }                                                                          \
    if (valid_) {                                                              \
        uint32x4 ov_ = {pkbf(p_[0], p_[1]), pkbf(p_[2], p_[3]),                \
                        pkbf(p_[4], p_[5]), pkbf(p_[6], p_[7])};               \
        *(uint32x4*)(z1 + (size_t)e_ * 128 + colg * 8) = ov_;                  \
    }                                                                          \
} while (0)

__global__ __launch_bounds__(256) void edge_z1_k(
    const short* __restrict__ xs1b, const short* __restrict__ xt1b,
    const short* __restrict__ tabN,
    const ERec* __restrict__ rec,
    short* __restrict__ z1, float* __restrict__ stats, int Etot)
{
    int tid = threadIdx.x, wave = tid >> 6, lane = tid & 63;
    int colg = lane & 15, esub = lane >> 4;

    int gw = blockIdx.x * 4 + wave;          // global wave id
    int W = gridDim.x * 4;                   // total waves
    int nq = (Etot + 3) >> 2;                // total 4-edge quads
    int q0 = (int)(((long long)gw * nq) / W);
    int q1 = (int)(((long long)(gw + 1) * nq) / W);
    int nsteps = q1 - q0;                    // balanced to +-1

    float sacc[8], qacc[8];
    #pragma unroll
    for (int j = 0; j < 8; j++) { sacc[j] = 0.f; qacc[j] = 0.f; }

    bf16x8 xsA, xtA, ttA[4];
    bf16x8 xsB, xtB, ttB[4];
    bf16x8 xsC, xtC, ttC[4];

    if (nsteps > 0) {
        EZ_ISSUE(xsA, xtA, ttA, q0 + 0);
        EZ_ISSUE(xsB, xtB, ttB, q0 + 1);     // clamped if overshoot
        int st = 0;
        for (; st + 3 <= nsteps; st += 3) {
            EZ_ISSUE(xsC, xtC, ttC, q0 + st + 2);
            EZ_CONSUME(xsA, xtA, ttA, q0 + st);
            EZ_ISSUE(xsA, xtA, ttA, q0 + st + 3);
            EZ_CONSUME(xsB, xtB, ttB, q0 + st + 1);
            EZ_ISSUE(xsB, xtB, ttB, q0 + st + 4);
            EZ_CONSUME(xsC, xtC, ttC, q0 + st + 2);
        }
        if (st < nsteps)
            EZ_CONSUME(xsA, xtA, ttA, q0 + st);
        if (st + 1 < nsteps)
            EZ_CONSUME(xsB, xtB, ttB, q0 + st + 1);
    }

    // pre-reduce across the 4 esub lanes sharing a column group (lanes
    // colg, colg+16, colg+32, colg+48) -> 4x fewer LDS atomics
    #pragma unroll
    for (int j = 0; j < 8; j++) {
        sacc[j] += __shfl_xor(sacc[j], 16);
        sacc[j] += __shfl_xor(sacc[j], 32);
        qacc[j] += __shfl_xor(qacc[j], 16);
        qacc[j] += __shfl_xor(qacc[j], 32);
    }

    __shared__ float lS[128], lQ[128];
    if (tid < 128) { lS[tid] = 0.f; lQ[tid] = 0.f; }
    __syncthreads();
    if (esub == 0) {
        #pragma unroll
        for (int j = 0; j < 8; j++) {
            atomicAdd(&lS[colg * 8 + j], sacc[j]);
            atomicAdd(&lQ[colg * 8 + j], qacc[j]);
        }
    }
    __syncthreads();
    if (tid < 128) {
        int rep = blockIdx.x & 15;
        atomicAdd(&stats[rep * 256 + tid], lS[tid]);
        atomicAdd(&stats[rep * 256 + 128 + tid], lQ[tid]);
    }
}

// ---------------- segmented reduce over dst-sorted edges (no atomics) ----
// 8 dsts/wave. Segment bounds computed from posE/bsum/cnt (fix_k removed):
// s0 = posE[d] + bsum[d>>8]; s1 = s0 + cnt[d].
__global__ __launch_bounds__(256) void segred_k(
    const short* __restrict__ cond, const short* __restrict__ xd,
    const ERec* __restrict__ rec,
    const int* __restrict__ posE, const int* __restrict__ bsum,
    const int* __restrict__ cnt,
    short* __restrict__ zaccb, int Nn)
{
    int tid = threadIdx.x, wave = tid >> 6, lane = tid & 63;
    int colg = lane & 7;        // 8 col-groups x 16 cols
    int esub = lane >> 3;       // 8 edges in parallel
    int d0 = blockIdx.x * 32 + wave * 8;

    for (int i = 0; i < 8; i++) {
        int d = d0 + i;
        if (d >= Nn) break;
        int s0 = posE[d] + bsum[d >> 8];
        int s1 = s0 + cnt[d];
        if (s1 <= s0) continue;            // empty segment: zaccb already = m_t

        float acc[16];
        #pragma unroll
        for (int j = 0; j < 16; j++) acc[j] = 0.f;

        for (int t = s0 + esub; t < s1; t += 8) {
            const short* cp = cond + (size_t)t * 128 + colg * 16;
            bf16x8 c0 = *(const bf16x8*)cp;
            bf16x8 c1 = *(const bf16x8*)(cp + 8);
            int s = rec[t].src;
            const short* xp = xd + (size_t)s * 128 + colg * 16;
            bf16x8 x0 = *(const bf16x8*)xp;
            bf16x8 x1 = *(const bf16x8*)(xp + 8);
            #pragma unroll
            for (int j = 0; j < 8; j++) {
                acc[j]     += bf2f(c0[j]) * bf2f(x0[j]);
                acc[8 + j] += bf2f(c1[j]) * bf2f(x1[j]);
            }
        }

        #pragma unroll
        for (int j = 0; j < 16; j++) {
            acc[j] += __shfl_xor(acc[j], 8);
            acc[j] += __shfl_xor(acc[j], 16);
            acc[j] += __shfl_xor(acc[j], 32);
        }

        if (esub == 0) {
            short* zp = zaccb + (size_t)d * 128 + colg * 16;
            bf16x8 z0 = *(const bf16x8*)zp;
            bf16x8 z1 = *(const bf16x8*)(zp + 8);
            bf16x8 o0, o1;
            #pragma unroll
            for (int j = 0; j < 8; j++) {
                o0[j] = f2bf(bf2f(z0[j]) + acc[j]);
                o1[j] = f2bf(bf2f(z1[j]) + acc[8 + j]);
            }
            *(bf16x8*)zp = o0;
            *(bf16x8*)(zp + 8) = o1;
        }
    }
}

// ---------------- persistent MFMA GEMM, balanced ranges, unroll-2 A pipeline --
// EPI2 epilogue = R11 form (zz_ array; measured fastest). EPI3 cf at epilogue.
// EPI 2: z=lrelu(val); out bf16; BN stats
// EPI 3: out bf16 = rec[row].cf * val   (cond_filter, in-place over A)
// EPI 4: out fp32 = val + xres

#define PG_LOADA(AF, ci) do {                                                  \
    int rowA_ = (ci) * 64 + wave * 16 + colbase;                               \
    bool rv_ = ((ci) < cend) && (rowA_ < M);                                   \
    _Pragma("unroll")                                                          \
    for (int ks_ = 0; ks_ < 4; ks_++)                                          \
        AF[ks_] = rv_ ? *(const bf16x8*)(A + (size_t)rowA_ * 128 + ks_ * 32 + kgrp * 8) \
                      : (bf16x8){0,0,0,0,0,0,0,0};                             \
} while (0)

#define PG_PROC(AF, ci) do {                                                   \
    int rbase_ = (ci) * 64 + wave * 16 + kgrp * 4;                             \
    f32x4 acc_[8];                                                             \
    _Pragma("unroll")                                                          \
    for (int n_ = 0; n_ < 8; n_++) acc_[n_] = (f32x4){0.f, 0.f, 0.f, 0.f};     \
    _Pragma("unroll")                                                          \
    for (int ks_ = 0; ks_ < 4; ks_++) {                                        \
        _Pragma("unroll")                                                      \
        for (int n_ = 0; n_ < 8; n_++) {                                       \
            bf16x8 bf_ = *(const bf16x8*)(ldsB + ((size_t)((n_ * 4 + ks_) * 64 + lane)) * 8); \
            acc_[n_] = __builtin_amdgcn_mfma_f32_16x16x32_bf16(AF[ks_], bf_, acc_[n_], 0, 0, 0); \
        }                                                                      \
    }                                                                          \
    if (EPI == 2) {                                                            \
        short* outh_ = (short*)out;                                            \
        _Pragma("unroll")                                                      \
        for (int r_ = 0; r_ < 4; r_++) {                                       \
            int row_ = rbase_ + r_;                                            \
            float zz_[8];                                                      \
            _Pragma("unroll")                                                  \
            for (int n_ = 0; n_ < 8; n_++) {                                   \
                float z_ = acc_[n_][r_] + bcol[n_];                            \
                z_ = z_ >= 0.f ? z_ : 0.01f * z_;                              \
                if (row_ >= M) z_ = 0.f;                                       \
                sreg[n_] += z_; qreg[n_] += z_ * z_;                           \
                zz_[n_] = z_;                                                  \
            }                                                                  \
            if (row_ < M) {                                                    \
                uint32x4 ov_ = {pkbf(zz_[0], zz_[1]), pkbf(zz_[2], zz_[3]),    \
                                pkbf(zz_[4], zz_[5]), pkbf(zz_[6], zz_[7])};   \
                *(uint32x4*)(outh_ + (size_t)row_ * 128 + colbase * 8) = ov_;  \
            }                                                                  \
        }                                                                      \
    } else if (EPI == 3) {                                                     \
        short* outh_ = (short*)out;                                            \
        _Pragma("unroll")                                                      \
        for (int r_ = 0; r_ < 4; r_++) {                                       \
            int row_ = rbase_ + r_;                                            \
            if (row_ < M) {                                                    \
                float cfv_ = rec[row_].cf;                                     \
                uint32x4 ov_;                                                  \
                _Pragma("unroll")                                              \
                for (int q_ = 0; q_ < 4; q_++)                                 \
                    ov_[q_] = pkbf(cfv_ * (acc_[2 * q_][r_] + bcol[2 * q_]),   \
                                   cfv_ * (acc_[2 * q_ + 1][r_] + bcol[2 * q_ + 1])); \
                *(uint32x4*)(outh_ + (size_t)row_ * 128 + colbase * 8) = ov_;  \
            }                                                                  \
        }                                                                      \
    } else if (EPI == 4) {                                                     \
        float* outf_ = (float*)out;                                            \
        _Pragma("unroll")                                                      \
        for (int r_ = 0; r_ < 4; r_++) {                                       \
            int row_ = rbase_ + r_;                                            \
            if (row_ < M) {                                                    \
                const float4* xr_ = (const float4*)(xres + (size_t)row_ * 128 + colbase * 8); \
                float4 x0_ = xr_[0], x1_ = xr_[1];                             \
                float4 o0_, o1_;                                               \
                o0_.x = acc_[0][r_] + bcol[0] + x0_.x;                         \
                o0_.y = acc_[1][r_] + bcol[1] + x0_.y;                         \
                o0_.z = acc_[2][r_] + bcol[2] + x0_.z;                         \
                o0_.w = acc_[3][r_] + bcol[3] + x0_.w;                         \
                o1_.x = acc_[4][r_] + bcol[4] + x1_.x;                         \
                o1_.y = acc_[5][r_] + bcol[5] + x1_.y;                         \
                o1_.z = acc_[6][r_] + bcol[6] + x1_.z;                         \
                o1_.w = acc_[7][r_] + bcol[7] + x1_.w;                         \
                float4* op_ = (float4*)(outf_ + (size_t)row_ * 128 + colbase * 8); \
                op_[0] = o0_; op_[1] = o1_;                                    \
            }                                                                  \
        }                                                                      \
    }                                                                          \
} while (0)

template<int EPI>
__global__ __launch_bounds__(256, 2) void pgemm_k(
    const short* __restrict__ A, int M,
    const short* __restrict__ Bp, const float* __restrict__ bias,
    void* __restrict__ out, float* __restrict__ stats,
    const ERec* __restrict__ rec, const float* __restrict__ xres)
{
    __shared__ __align__(16) short ldsB[16384];
    __shared__ float lS[128], lQ[128];
    int tid = threadIdx.x;
    int wave = tid >> 6, lane = tid & 63;
    int kgrp = lane >> 4, colbase = lane & 15;

    // async stage B -> LDS once: 8 issues x (4 waves x 64 lanes x 16B) = 32KB
    #pragma unroll
    for (int i = 0; i < 8; i++) {
        int off = (i * 256 + wave * 64 + lane) * 8;   // shorts; lane-contiguous
        GLD_LDS16(Bp + off, ldsB + off);
    }

    int nch = (M + 63) >> 6;
    // balanced contiguous chunk range for this block
    int cbeg = (int)(((long long)blockIdx.x * nch) / gridDim.x);
    int cend = (int)(((long long)(blockIdx.x + 1) * nch) / gridDim.x);

    // prologue: A fragments for the first two chunks
    bf16x8 afA[4], afB[4];
    PG_LOADA(afA, cbeg);
    PG_LOADA(afB, cbeg + 1);

    float bcol[8];
    *(float4*)&bcol[0] = *(const float4*)(bias + colbase * 8);
    *(float4*)&bcol[4] = *(const float4*)(bias + colbase * 8 + 4);

    float sreg[8], qreg[8];
    if (EPI == 2) {
        #pragma unroll
        for (int n = 0; n < 8; n++) { sreg[n] = 0.f; qreg[n] = 0.f; }
        if (tid < 128) { lS[tid] = 0.f; lQ[tid] = 0.f; }
    }

    __syncthreads();   // B staged (once per block for the whole dispatch)

    int c = cbeg;
    for (; c + 1 < cend; c += 2) {
        PG_PROC(afA, c);            // consume afA (loads issued 2 chunks ago)
        PG_LOADA(afA, c + 2);       // refill AFTER consumption: 2-chunk lead
        PG_PROC(afB, c + 1);
        PG_LOADA(afB, c + 3);
    }
    if (c < cend)
        PG_PROC(afA, c);            // odd tail

    if (EPI == 2) {
        // pre-reduce across the 4 kgrp lanes sharing colbase -> 4x fewer atomics
        #pragma unroll
        for (int n = 0; n < 8; n++) {
            sreg[n] += __shfl_xor(sreg[n], 16);
            sreg[n] += __shfl_xor(sreg[n], 32);
            qreg[n] += __shfl_xor(qreg[n], 16);
            qreg[n] += __shfl_xor(qreg[n], 32);
        }
        __syncthreads();
        if (kgrp == 0) {
            #pragma unroll
            for (int n = 0; n < 8; n++) {
                atomicAdd(&lS[colbase * 8 + n], sreg[n]);
                atomicAdd(&lQ[colbase * 8 + n], qreg[n]);
            }
        }
        __syncthreads();
        if (tid < 128) {
            int rep = blockIdx.x & 15;
            atomicAdd(&stats[rep * 256 + tid], lS[tid]);
            atomicAdd(&stats[rep * 256 + 128 + tid], lQ[tid]);
        }
    }
}

extern "C" void kernel_launch(void* const* d_in, const int* in_sizes, int n_in,
                              void* d_out, int out_size, void* d_ws, size_t ws_size,
                              hipStream_t stream)
{
    const float* x    = (const float*)d_in[0];
    const float* ea   = (const float*)d_in[1];
    const int*   eidx = (const int*)d_in[2];
    const float* Wb   = (const float*)d_in[3];
    const float* bb   = (const float*)d_in[4];
    const float* We1  = (const float*)d_in[5];
    const float* be1  = (const float*)d_in[6];
    const float* ge1  = (const float*)d_in[7];
    const float* bte1 = (const float*)d_in[8];
    const float* We2  = (const float*)d_in[9];
    const float* be2  = (const float*)d_in[10];
    const float* ge2  = (const float*)d_in[11];
    const float* bte2 = (const float*)d_in[12];
    const float* We3  = (const float*)d_in[13];
    const float* be3  = (const float*)d_in[14];
    const float* Wd   = (const float*)d_in[15];
    const float* bd   = (const float*)d_in[16];
    const float* vv   = (const float*)d_in[17];
    const float* Wn1  = (const float*)d_in[18];
    const float* bn1  = (const float*)d_in[19];
    const float* gn   = (const float*)d_in[20];
    const float* btn  = (const float*)d_in[21];
    const float* Wn2  = (const float*)d_in[22];
    const float* bn2  = (const float*)d_in[23];

    const int NN = in_sizes[0] / 128;   // 50000
    const int EE = in_sizes[1] / 4;     // 300000

    char* ws = (char*)d_ws;
    size_t oEZ   = 0;
    size_t oXD   = oEZ   + (size_t)EE * 256;
    size_t oXS   = oXD   + (size_t)NN * 256;
    size_t oXT   = oXS   + (size_t)NN * 256;
    size_t oZACC = oXT   + (size_t)NN * 256;
    size_t oZN   = oZACC + (size_t)NN * 256;
    size_t oTAB  = oZN   + (size_t)NN * 256;
    size_t oW1P  = oTAB  + (size_t)4 * 1024 * 256;   // nearest table: 1MB
    size_t oB1P  = oW1P  + (size_t)200 * 512;
    size_t oBP   = oB1P  + 512;
    size_t oBIAS = oBP   + (size_t)7 * 32768;
    size_t oST   = oBIAS + (size_t)7 * 512;
    size_t oCNT  = oST   + 49152;                    // hist counts
    size_t oCNT2 = oCNT  + 201728;                   // scat running counters (zeroed)
    size_t oPOS  = oCNT2 + 201728;
    size_t oBSUM = oPOS  + 201728;
    size_t oREC  = (oBSUM + 1024 + 31) & ~(size_t)31;   // EE x 32B records

    short* eZ    = (short*)(ws + oEZ);
    short* xd    = (short*)(ws + oXD);
    short* xs1b  = (short*)(ws + oXS);
    short* xt1b  = (short*)(ws + oXT);
    short* zaccb = (short*)(ws + oZACC);
    short* zn    = (short*)(ws + oZN);
    short* tabN  = (short*)(ws + oTAB);
    float* W1p   = (float*)(ws + oW1P);
    float* b1p   = (float*)(ws + oB1P);
    short* bp    = (short*)(ws + oBP);
    short* BpW2  = bp + 3 * 16384;
    short* BpW3  = bp + 4 * 16384;
    short* BpN1  = bp + 5 * 16384;
    short* BpN2  = bp + 6 * 16384;
    float* bo    = (float*)(ws + oBIAS);
    float* b2p   = bo + 0 * 128;
    float* b3p   = bo + 1 * 128;
    float* b2np  = bo + 2 * 128;
    float* st1   = (float*)(ws + oST);
    float* st2   = st1 + 4096;
    float* stN   = st1 + 8192;
    int*   cnt   = (int*)(ws + oCNT);
    int*   cnt2  = (int*)(ws + oCNT2);
    int*   posE  = (int*)(ws + oPOS);
    int*   bsum  = (int*)(ws + oBSUM);
    ERec*  rec   = (ERec*)(ws + oREC);

    // zero stats + cnt + cnt2
    hipMemsetAsync(ws + oST, 0, 49152 + 2 * 201728, stream);

    prep_k<<<233, 256, 0, stream>>>(Wb, We1, bb, be1, W1p, b1p,
        Wd, We1, We1 + 256 * 128, Wn1, bp, bp + 16384, bp + 2 * 16384, BpN1);
    build_tab_k<<<dim3(1024, 4), 128, 0, stream>>>(W1p, b1p, tabN);

    int nchN = (NN + 63) / 64;
    int nchE = (EE + 63) / 64;
    int nbN = (NN + 255) / 256;
    int nbE = (EE + 255) / 256;
    int nbSeg = (NN + 31) / 32;         // segred: 32 dsts/block (8/wave)

    // persistent grids: at most the resident capacity (4 blocks/CU x 256 CU)
    int gridEz = 1024;
    int gridE = nchE < 1024 ? nchE : 1024;
    int gridN = nchN < 1024 ? nchN : 1024;   // 782: exactly 1 chunk/block

    // fused node precompute: xd/zacc, xs1, xt1  (reads x once)
    node_all_k<<<nchN, 256, 0, stream>>>(x, NN, bp, bd, vv, xd, zaccb, xs1b, xt1b);

    // counting sort by dst (fix_k eliminated: offsets computed inline)
    hist_k<<<nbE, 256, 0, stream>>>(eidx + EE, cnt, EE);
    scan1_k<<<nbN, 256, 0, stream>>>(cnt, NN, posE, bsum);
    scan2_k<<<1, 256, 0, stream>>>(bsum, nbN);
    scat_k<<<nbE, 256, 0, stream>>>(eidx, eidx + EE, (const float4*)ea,
                                    posE, bsum, cnt2, rec, EE);

    edge_z1_k<<<gridEz, 256, 0, stream>>>(xs1b, xt1b, tabN, rec, eZ, st1, EE);

    fold_k<<<8, 256, 0, stream>>>(We2, be2, st1, ge1, bte1, 1.f / (float)EE, BpW2, b2p);
    pgemm_k<2><<<gridE, 256, 0, stream>>>(eZ, EE, BpW2, b2p, eZ, st2,
        nullptr, nullptr);

    fold_k<<<8, 256, 0, stream>>>(We3, be3, st2, ge2, bte2, 1.f / (float)EE, BpW3, b3p);
    // cond_filter = cf * (z2 @ W3f + b3), written in-place over eZ
    pgemm_k<3><<<gridE, 256, 0, stream>>>(eZ, EE, BpW3, b3p, eZ, nullptr,
        rec, nullptr);

    // segmented reduction (dst-sorted): zaccb += sum cond*xd[src]
    segred_k<<<nbSeg, 256, 0, stream>>>(eZ, xd, rec, posE, bsum, cnt, zaccb, NN);

    pgemm_k<2><<<gridN, 256, 0, stream>>>(zaccb, NN, BpN1, bn1, zn, stN,
        nullptr, nullptr);

    fold_k<<<8, 256, 0, stream>>>(Wn2, bn2, stN, gn, btn, 1.f / (float)NN, BpN2, b2np);
    pgemm_k<4><<<gridN, 256, 0, stream>>>(zn, NN, BpN2, b2np, d_out, nullptr,
        nullptr, x);
}